// Round 2
// baseline (2845.954 us; speedup 1.0000x reference)
//
#include <hip/hip_runtime.h>
#include <hip/hip_bf16.h>

#define HIDC 768
#define Hh   6
#define Dd   64
#define AHc  384
#define KSc  9
#define PADc 4
#define Bb   4
#define Ss   1024

// ---------------- transpose pw_w (AH x HID) -> pwT (HID x AH) ----------------
__global__ void k_transpose_pw(const float* __restrict__ pw, float* __restrict__ pwT) {
    int idx = blockIdx.x * 256 + threadIdx.x;      // over HID*AH, idx = c*AH + o
    if (idx >= HIDC * AHc) return;
    int o = idx % AHc, c = idx / AHc;
    pwT[idx] = pw[o * HIDC + c];
}

// ---------------- depthwise conv over sequence: dwseq[b,s,c] ----------------
__global__ void k_depthwise(const float* __restrict__ Kin, const float* __restrict__ dww,
                            float* __restrict__ dwseq) {
    int idx = blockIdx.x * 256 + threadIdx.x;      // over B*S*HID
    if (idx >= Bb * Ss * HIDC) return;
    int c = idx % HIDC;
    int s = (idx / HIDC) % Ss;
    int b = idx / (HIDC * Ss);
    float acc = 0.f;
#pragma unroll
    for (int k = 0; k < KSc; ++k) {
        int sp = s + k - PADc;
        if (sp >= 0 && sp < Ss)
            acc += Kin[(b * Ss + sp) * HIDC + c] * dww[c * KSc + k];
    }
    dwseq[idx] = acc;
}

// ---------------- tiled GEMM: C(MxN) = A(MxK) @ B(KxN) [+ bias] ----------------
__global__ __launch_bounds__(256) void k_gemm(const float* __restrict__ A, const float* __restrict__ B,
                                              const float* __restrict__ bias, float* __restrict__ C,
                                              int M, int N, int K) {
    __shared__ float As[16][64];
    __shared__ float Bs[16][65];
    int tid = threadIdx.x;
    int m0 = blockIdx.y * 64;
    int n0 = blockIdx.x * 64;
    int arow = tid >> 2;             // 0..63
    int acol = (tid & 3) * 4;        // 0..12
    int brow = tid >> 4;             // 0..15
    int bcol = (tid & 15) * 4;       // 0..60
    int ty = tid >> 4, tx = tid & 15;
    float acc[4][4] = {};
    for (int k0 = 0; k0 < K; k0 += 16) {
        float4 av4 = *(const float4*)&A[(size_t)(m0 + arow) * K + k0 + acol];
        As[acol + 0][arow] = av4.x;
        As[acol + 1][arow] = av4.y;
        As[acol + 2][arow] = av4.z;
        As[acol + 3][arow] = av4.w;
        float4 bv4 = *(const float4*)&B[(size_t)(k0 + brow) * N + n0 + bcol];
        Bs[brow][bcol + 0] = bv4.x;
        Bs[brow][bcol + 1] = bv4.y;
        Bs[brow][bcol + 2] = bv4.z;
        Bs[brow][bcol + 3] = bv4.w;
        __syncthreads();
#pragma unroll
        for (int kk = 0; kk < 16; ++kk) {
            float av[4], bv[4];
#pragma unroll
            for (int r = 0; r < 4; ++r) av[r] = As[kk][ty * 4 + r];
#pragma unroll
            for (int c = 0; c < 4; ++c) bv[c] = Bs[kk][tx * 4 + c];
#pragma unroll
            for (int r = 0; r < 4; ++r)
#pragma unroll
                for (int c = 0; c < 4; ++c) acc[r][c] += av[r] * bv[c];
        }
        __syncthreads();
    }
#pragma unroll
    for (int c = 0; c < 4; ++c) {
        float bv = bias ? bias[n0 + tx * 4 + c] : 0.f;
#pragma unroll
        for (int r = 0; r < 4; ++r)
            C[(size_t)(m0 + ty * 4 + r) * N + n0 + tx * 4 + c] = acc[r][c] + bv;
    }
}

// ---------------- conv_attn -> ck linear -> per-head softmax over KS ----------------
__global__ __launch_bounds__(64) void k_ck(const float* __restrict__ mkc, const float* __restrict__ mq,
                                           const float* __restrict__ ckW, const float* __restrict__ ckb,
                                           float* __restrict__ ck_sm) {
    int row = blockIdx.x;            // b*S + s
    int tid = threadIdx.x;
    __shared__ float ca[AHc];
    __shared__ float ckv[Hh * KSc];
    for (int o = tid; o < AHc; o += 64)
        ca[o] = mkc[row * AHc + o] * mq[row * AHc + o];
    __syncthreads();
    if (tid < Hh * KSc) {
        float acc = ckb[tid];
        for (int o = 0; o < AHc; ++o)
            acc += ca[o] * ckW[o * (Hh * KSc) + tid];
        ckv[tid] = acc;
    }
    __syncthreads();
    if (tid < Hh) {
        float m = -3e38f;
#pragma unroll
        for (int k = 0; k < KSc; ++k) m = fmaxf(m, ckv[tid * KSc + k]);
        float e[KSc];
        float s = 0.f;
#pragma unroll
        for (int k = 0; k < KSc; ++k) { e[k] = expf(ckv[tid * KSc + k] - m); s += e[k]; }
        float inv = 1.f / s;
#pragma unroll
        for (int k = 0; k < KSc; ++k) ck_sm[(row * Hh + tid) * KSc + k] = e[k] * inv;
    }
}

// ---------------- dynamic conv output -> out[.., AH + h*D + d] ----------------
__global__ void k_convout(const float* __restrict__ co, const float* __restrict__ ck_sm,
                          float* __restrict__ out) {
    int idx = blockIdx.x * 256 + threadIdx.x;       // over B*S*AH
    if (idx >= Bb * Ss * AHc) return;
    int d = idx & 63;
    int h = (idx >> 6) % Hh;
    int s = (idx / AHc) % Ss;
    int b = idx / (AHc * Ss);
    int row = b * Ss + s;
    float acc = 0.f;
#pragma unroll
    for (int k = 0; k < KSc; ++k) {
        int sp = s + k - PADc;
        if (sp >= 0 && sp < Ss)
            acc += co[(size_t)(b * Ss + sp) * AHc + h * Dd + d] * ck_sm[(row * Hh + h) * KSc + k];
    }
    out[(size_t)row * (2 * AHc) + AHc + h * Dd + d] = acc;
}

// ---------------- per-batch td softmax row (i/h independent) ----------------
__global__ __launch_bounds__(256) void k_td(const float* __restrict__ td, const int* __restrict__ mask,
                                            float* __restrict__ td_sm) {
    int b = blockIdx.x;
    int tid = threadIdx.x;
    __shared__ float red[256];
    __shared__ float tv[Ss];
    float ls = 0.f;
    for (int j = tid; j < Ss; j += 256) {
        float v = td[b * Ss + j];
        tv[j] = v;
        ls += v * v;
    }
    red[tid] = ls; __syncthreads();
    for (int s = 128; s > 0; s >>= 1) { if (tid < s) red[tid] += red[tid + s]; __syncthreads(); }
    float norm = fmaxf(sqrtf(red[0]), 1e-12f);
    __syncthreads();
    float lm = -3e38f;
    for (int j = tid; j < Ss; j += 256) {
        float v = mask[b * Ss + j] ? tv[j] / norm : -1e4f;
        tv[j] = v;
        lm = fmaxf(lm, v);
    }
    red[tid] = lm; __syncthreads();
    for (int s = 128; s > 0; s >>= 1) { if (tid < s) red[tid] = fmaxf(red[tid], red[tid + s]); __syncthreads(); }
    float m = red[0]; __syncthreads();
    float lsum = 0.f;
    for (int j = tid; j < Ss; j += 256) {
        float e = expf(tv[j] - m);
        tv[j] = e;
        lsum += e;
    }
    red[tid] = lsum; __syncthreads();
    for (int s = 128; s > 0; s >>= 1) { if (tid < s) red[tid] += red[tid + s]; __syncthreads(); }
    float inv = 1.f / red[0];
    __syncthreads();
    for (int j = tid; j < Ss; j += 256)
        td_sm[b * Ss + j] = tv[j] * inv;
}

// ---------------- attention with distance decay: one block per (b,h,i) ----------------
__global__ __launch_bounds__(256) void k_attn(const float* __restrict__ mq, const float* __restrict__ mk,
                                              const float* __restrict__ mv, const int* __restrict__ mask,
                                              const float* __restrict__ td_sm, const float* __restrict__ gammas,
                                              float* __restrict__ out) {
    int blk = blockIdx.x;            // ((b*H + h) * S + i)
    int i  = blk & (Ss - 1);
    int bh = blk >> 10;
    int h  = bh % Hh;
    int b  = bh / Hh;
    int tid = threadIdx.x;
    __shared__ float sc[Ss];
    __shared__ float pr[Ss];
    __shared__ float qs[Dd];
    __shared__ float red[256];
    __shared__ float aux[256];

    if (tid < Dd) qs[tid] = mq[(size_t)(b * Ss + i) * AHc + h * Dd + tid];
    __syncthreads();

    const int* mrow = mask + b * Ss;
    float g = gammas[h];
    float gamma = -log1pf(expf(g));          // -softplus(g)

    // raw scores: q_i . k_j / sqrt(D)
    const float4* q4 = (const float4*)qs;
#pragma unroll
    for (int l = 0; l < 4; ++l) {
        int j = tid + l * 256;
        const float4* k4 = (const float4*)(mk + (size_t)(b * Ss + j) * AHc + h * Dd);
        float a = 0.f;
#pragma unroll
        for (int d4 = 0; d4 < 16; ++d4) {
            float4 qv = q4[d4], kv = k4[d4];
            a += qv.x * kv.x + qv.y * kv.y + qv.z * kv.z + qv.w * kv.w;
        }
        sc[j] = a * 0.125f;
    }

    // masked softmax -> p (unnormalized in pr, scale = inv)
    bool amv[4];
    float lmax = -3e38f;
#pragma unroll
    for (int l = 0; l < 4; ++l) {
        int j = tid + l * 256;
        amv[l] = (mrow[j] != 0);
        lmax = fmaxf(lmax, amv[l] ? sc[j] : -1e8f);
    }
    red[tid] = lmax; __syncthreads();
    for (int s = 128; s > 0; s >>= 1) { if (tid < s) red[tid] = fmaxf(red[tid], red[tid + s]); __syncthreads(); }
    float maxv = red[0]; __syncthreads();
    float lsum = 0.f;
#pragma unroll
    for (int l = 0; l < 4; ++l) {
        int j = tid + l * 256;
        float e = amv[l] ? expf(sc[j] - maxv) : 0.f;
        pr[j] = e;
        lsum += e;
    }
    red[tid] = lsum; __syncthreads();
    for (int s = 128; s > 0; s >>= 1) { if (tid < s) red[tid] += red[tid + s]; __syncthreads(); }
    float inv = 1.f / fmaxf(red[0], 1e-30f);
    __syncthreads();

    // inclusive cumsum of (unnormalized) p, thread owns pr[4t..4t+3]
    int base = tid * 4;
    float a0 = pr[base], a1 = pr[base + 1], a2 = pr[base + 2], a3 = pr[base + 3];
    a1 += a0; a2 += a1; a3 += a2;
    aux[tid] = a3; __syncthreads();
    for (int off = 1; off < 256; off <<= 1) {
        float t = aux[tid];
        if (tid >= off) t += aux[tid - off];
        __syncthreads();
        aux[tid] = t;
        __syncthreads();
    }
    float offv = (tid > 0) ? aux[tid - 1] : 0.f;
    float tot = aux[255];
    pr[base] = a0 + offv; pr[base + 1] = a1 + offv; pr[base + 2] = a2 + offv; pr[base + 3] = a3 + offv;
    __syncthreads();

    // decayed scores
    const float* tdrow = td_sm + b * Ss;
    float lmax2 = -3e38f;
#pragma unroll
    for (int l = 0; l < 4; ++l) {
        int j = tid + l * 256;
        float pos = fabsf((float)(j - i));
        float ds = sqrtf(fmaxf((tot - pr[j]) * inv * pos, 0.f));
        float te = fminf(fmaxf(expf(ds * gamma), 1e-5f), 1e5f);
        float mult = te - ((j < i) ? tdrow[j] : 0.f);
        float s2 = amv[l] ? sc[j] * mult : -1e8f;
        sc[j] = s2;
        lmax2 = fmaxf(lmax2, s2);
    }
    red[tid] = lmax2; __syncthreads();
    for (int s = 128; s > 0; s >>= 1) { if (tid < s) red[tid] = fmaxf(red[tid], red[tid + s]); __syncthreads(); }
    float m2 = red[0]; __syncthreads();
    float lsum2 = 0.f;
#pragma unroll
    for (int l = 0; l < 4; ++l) {
        int j = tid + l * 256;
        float e = expf(sc[j] - m2);
        pr[j] = e;                    // unnormalized probs
        lsum2 += e;
    }
    red[tid] = lsum2; __syncthreads();
    for (int s = 128; s > 0; s >>= 1) { if (tid < s) red[tid] += red[tid + s]; __syncthreads(); }
    float inv2 = 1.f / red[0];
    __syncthreads();

    // PV: ctx[d] = sum_j probs[j] * v[j,d]
    int d = tid & 63;
    int r = tid >> 6;
    const float* vcol = mv + (size_t)(b * Ss) * AHc + h * Dd + d;
    float acc = 0.f;
    int j0 = r * 256;
    for (int jj = j0; jj < j0 + 256; ++jj)
        acc += pr[jj] * vcol[(size_t)jj * AHc];
    aux[tid] = acc;
    __syncthreads();
    if (tid < 64) {
        float s = aux[tid] + aux[tid + 64] + aux[tid + 128] + aux[tid + 192];
        out[(size_t)(b * Ss + i) * (2 * AHc) + h * Dd + d] = s * inv2;
    }
}

extern "C" void kernel_launch(void* const* d_in, const int* in_sizes, int n_in,
                              void* d_out, int out_size, void* d_ws, size_t ws_size,
                              hipStream_t stream) {
    const float* Q    = (const float*)d_in[0];
    const float* Kin  = (const float*)d_in[1];
    const float* V    = (const float*)d_in[2];
    const float* td   = (const float*)d_in[3];
    const int*   mask = (const int*)d_in[4];
    const float* Wq   = (const float*)d_in[5];
    const float* Wk   = (const float*)d_in[6];
    const float* Wv   = (const float*)d_in[7];
    const float* dww  = (const float*)d_in[8];
    const float* pww  = (const float*)d_in[9];
    const float* sepb = (const float*)d_in[10];
    const float* ckW  = (const float*)d_in[11];
    const float* ckb  = (const float*)d_in[12];
    const float* coW  = (const float*)d_in[13];
    const float* cob  = (const float*)d_in[14];
    const float* gam  = (const float*)d_in[15];
    float* out = (float*)d_out;
    float* ws = (float*)d_ws;

    const int MR = Bb * Ss;                       // 4096 rows
    float* mq    = ws;                            // MR*AH
    float* mk    = mq    + (size_t)MR * AHc;      // MR*AH
    float* mv    = mk    + (size_t)MR * AHc;      // MR*AH
    float* co    = mv    + (size_t)MR * AHc;      // MR*AH
    float* mkc   = co    + (size_t)MR * AHc;      // MR*AH
    float* dwseq = mkc   + (size_t)MR * AHc;      // MR*HID
    float* pwT   = dwseq + (size_t)MR * HIDC;     // HID*AH
    float* cksm  = pwT   + (size_t)HIDC * AHc;    // MR*H*KS
    float* tdsm  = cksm  + (size_t)MR * Hh * KSc; // B*S

    k_transpose_pw<<<(HIDC * AHc + 255) / 256, 256, 0, stream>>>(pww, pwT);
    k_depthwise<<<(MR * HIDC + 255) / 256, 256, 0, stream>>>(Kin, dww, dwseq);

    dim3 g1(AHc / 64, MR / 64);
    k_gemm<<<g1, 256, 0, stream>>>(dwseq, pwT, sepb, mkc, MR, AHc, HIDC);
    k_gemm<<<g1, 256, 0, stream>>>(Q,   Wq,  nullptr, mq, MR, AHc, HIDC);
    k_gemm<<<g1, 256, 0, stream>>>(Kin, Wk,  nullptr, mk, MR, AHc, HIDC);
    k_gemm<<<g1, 256, 0, stream>>>(V,   Wv,  nullptr, mv, MR, AHc, HIDC);
    k_gemm<<<g1, 256, 0, stream>>>(V,   coW, cob,     co, MR, AHc, HIDC);

    k_ck<<<MR, 64, 0, stream>>>(mkc, mq, ckW, ckb, cksm);
    k_convout<<<(MR * AHc + 255) / 256, 256, 0, stream>>>(co, cksm, out);
    k_td<<<Bb, 256, 0, stream>>>(td, mask, tdsm);
    k_attn<<<Bb * Hh * Ss, 256, 0, stream>>>(mq, mk, mv, mask, tdsm, gam, out);
}

// Round 3
// 975.796 us; speedup vs baseline: 2.9165x; 2.9165x over previous
//
#include <hip/hip_runtime.h>
#include <hip/hip_bf16.h>

#define HIDC 768
#define Hh   6
#define Dd   64
#define AHc  384
#define KSc  9
#define PADc 4
#define Bb   4
#define Ss   1024

// ---------------- transpose pw_w (AH x HID) -> pwT (HID x AH) ----------------
__global__ void k_transpose_pw(const float* __restrict__ pw, float* __restrict__ pwT) {
    int idx = blockIdx.x * 256 + threadIdx.x;      // over HID*AH, idx = c*AH + o
    if (idx >= HIDC * AHc) return;
    int o = idx % AHc, c = idx / AHc;
    pwT[idx] = pw[o * HIDC + c];
}

// ---------------- depthwise conv over sequence: dwseq[b,s,c] ----------------
__global__ void k_depthwise(const float* __restrict__ Kin, const float* __restrict__ dww,
                            float* __restrict__ dwseq) {
    int idx = blockIdx.x * 256 + threadIdx.x;      // over B*S*HID
    if (idx >= Bb * Ss * HIDC) return;
    int c = idx % HIDC;
    int s = (idx / HIDC) % Ss;
    int b = idx / (HIDC * Ss);
    float acc = 0.f;
#pragma unroll
    for (int k = 0; k < KSc; ++k) {
        int sp = s + k - PADc;
        if (sp >= 0 && sp < Ss)
            acc += Kin[(b * Ss + sp) * HIDC + c] * dww[c * KSc + k];
    }
    dwseq[idx] = acc;
}

// ---------------- tiled GEMM: C(MxN) = A(MxK) @ B(KxN) [+ bias] ----------------
__global__ __launch_bounds__(256) void k_gemm(const float* __restrict__ A, const float* __restrict__ B,
                                              const float* __restrict__ bias, float* __restrict__ C,
                                              int M, int N, int K) {
    __shared__ float As[16][64];
    __shared__ float Bs[16][65];
    int tid = threadIdx.x;
    int m0 = blockIdx.y * 64;
    int n0 = blockIdx.x * 64;
    int arow = tid >> 2;             // 0..63
    int acol = (tid & 3) * 4;        // 0..12
    int brow = tid >> 4;             // 0..15
    int bcol = (tid & 15) * 4;       // 0..60
    int ty = tid >> 4, tx = tid & 15;
    float acc[4][4] = {};
    for (int k0 = 0; k0 < K; k0 += 16) {
        float4 av4 = *(const float4*)&A[(size_t)(m0 + arow) * K + k0 + acol];
        As[acol + 0][arow] = av4.x;
        As[acol + 1][arow] = av4.y;
        As[acol + 2][arow] = av4.z;
        As[acol + 3][arow] = av4.w;
        float4 bv4 = *(const float4*)&B[(size_t)(k0 + brow) * N + n0 + bcol];
        Bs[brow][bcol + 0] = bv4.x;
        Bs[brow][bcol + 1] = bv4.y;
        Bs[brow][bcol + 2] = bv4.z;
        Bs[brow][bcol + 3] = bv4.w;
        __syncthreads();
#pragma unroll
        for (int kk = 0; kk < 16; ++kk) {
            float av[4], bv[4];
#pragma unroll
            for (int r = 0; r < 4; ++r) av[r] = As[kk][ty * 4 + r];
#pragma unroll
            for (int c = 0; c < 4; ++c) bv[c] = Bs[kk][tx * 4 + c];
#pragma unroll
            for (int r = 0; r < 4; ++r)
#pragma unroll
                for (int c = 0; c < 4; ++c) acc[r][c] += av[r] * bv[c];
        }
        __syncthreads();
    }
#pragma unroll
    for (int c = 0; c < 4; ++c) {
        float bv = bias ? bias[n0 + tx * 4 + c] : 0.f;
#pragma unroll
        for (int r = 0; r < 4; ++r)
            C[(size_t)(m0 + ty * 4 + r) * N + n0 + tx * 4 + c] = acc[r][c] + bv;
    }
}

// ---------------- conv_attn -> ck linear -> per-head softmax over KS ----------------
__global__ __launch_bounds__(64) void k_ck(const float* __restrict__ mkc, const float* __restrict__ mq,
                                           const float* __restrict__ ckW, const float* __restrict__ ckb,
                                           float* __restrict__ ck_sm) {
    int row = blockIdx.x;            // b*S + s
    int tid = threadIdx.x;
    __shared__ float ca[AHc];
    __shared__ float ckv[Hh * KSc];
    for (int o = tid; o < AHc; o += 64)
        ca[o] = mkc[row * AHc + o] * mq[row * AHc + o];
    __syncthreads();
    if (tid < Hh * KSc) {
        float acc = ckb[tid];
        for (int o = 0; o < AHc; ++o)
            acc += ca[o] * ckW[o * (Hh * KSc) + tid];
        ckv[tid] = acc;
    }
    __syncthreads();
    if (tid < Hh) {
        float m = -3e38f;
#pragma unroll
        for (int k = 0; k < KSc; ++k) m = fmaxf(m, ckv[tid * KSc + k]);
        float e[KSc];
        float s = 0.f;
#pragma unroll
        for (int k = 0; k < KSc; ++k) { e[k] = expf(ckv[tid * KSc + k] - m); s += e[k]; }
        float inv = 1.f / s;
#pragma unroll
        for (int k = 0; k < KSc; ++k) ck_sm[(row * Hh + tid) * KSc + k] = e[k] * inv;
    }
}

// ---------------- dynamic conv output -> out[.., AH + h*D + d] ----------------
__global__ void k_convout(const float* __restrict__ co, const float* __restrict__ ck_sm,
                          float* __restrict__ out) {
    int idx = blockIdx.x * 256 + threadIdx.x;       // over B*S*AH
    if (idx >= Bb * Ss * AHc) return;
    int d = idx & 63;
    int h = (idx >> 6) % Hh;
    int s = (idx / AHc) % Ss;
    int b = idx / (AHc * Ss);
    int row = b * Ss + s;
    float acc = 0.f;
#pragma unroll
    for (int k = 0; k < KSc; ++k) {
        int sp = s + k - PADc;
        if (sp >= 0 && sp < Ss)
            acc += co[(size_t)(b * Ss + sp) * AHc + h * Dd + d] * ck_sm[(row * Hh + h) * KSc + k];
    }
    out[(size_t)row * (2 * AHc) + AHc + h * Dd + d] = acc;
}

// ---------------- per-batch td softmax row (i/h independent) ----------------
__global__ __launch_bounds__(256) void k_td(const float* __restrict__ td, const int* __restrict__ mask,
                                            float* __restrict__ td_sm) {
    int b = blockIdx.x;
    int tid = threadIdx.x;
    __shared__ float red[256];
    __shared__ float tv[Ss];
    float ls = 0.f;
    for (int j = tid; j < Ss; j += 256) {
        float v = td[b * Ss + j];
        tv[j] = v;
        ls += v * v;
    }
    red[tid] = ls; __syncthreads();
    for (int s = 128; s > 0; s >>= 1) { if (tid < s) red[tid] += red[tid + s]; __syncthreads(); }
    float norm = fmaxf(sqrtf(red[0]), 1e-12f);
    __syncthreads();
    float lm = -3e38f;
    for (int j = tid; j < Ss; j += 256) {
        float v = mask[b * Ss + j] ? tv[j] / norm : -1e4f;
        tv[j] = v;
        lm = fmaxf(lm, v);
    }
    red[tid] = lm; __syncthreads();
    for (int s = 128; s > 0; s >>= 1) { if (tid < s) red[tid] = fmaxf(red[tid], red[tid + s]); __syncthreads(); }
    float m = red[0]; __syncthreads();
    float lsum = 0.f;
    for (int j = tid; j < Ss; j += 256) {
        float e = expf(tv[j] - m);
        tv[j] = e;
        lsum += e;
    }
    red[tid] = lsum; __syncthreads();
    for (int s = 128; s > 0; s >>= 1) { if (tid < s) red[tid] += red[tid + s]; __syncthreads(); }
    float inv = 1.f / red[0];
    __syncthreads();
    for (int j = tid; j < Ss; j += 256)
        td_sm[b * Ss + j] = tv[j] * inv;
}

// ---------------- attention: 4 waves/block, each wave owns 2 query rows ----------------
// lane = (g, c): g = lane>>4 selects one of 4 parallel j-subrows, c = lane&15 is the
// 4-float d-chunk. K/V reads are fully-coalesced float4 (1 KiB/wave/instr). All
// reductions/scans are wave-level shuffles — only 2 block barriers total.
// LDS score rows use a 17-dword stride per 16-j chunk => conflict-free for both the
// per-j scatter writes and the lane-owns-16-contiguous-j reads.
#define LROW 1088   // 64 chunks * 17 dwords
__device__ __forceinline__ int lds_idx(int j) { return (j >> 4) * 17 + (j & 15); }

__global__ __launch_bounds__(256) void k_attn(const float* __restrict__ mq, const float* __restrict__ mk,
                                              const float* __restrict__ mv, const int* __restrict__ mask,
                                              const float* __restrict__ td_sm, const float* __restrict__ gammas,
                                              float* __restrict__ out) {
    int blk = blockIdx.x;                 // 3072 blocks
    int i0 = (blk & 127) << 3;            // 8 rows per block
    int bh = blk >> 7;
    int h = bh % Hh;
    int b = bh / Hh;
    int tid = threadIdx.x;
    int wave = tid >> 6, lane = tid & 63;
    int g = lane >> 4, c = lane & 15;

    __shared__ float srow[4][2][LROW];    // [wave][row][padded 1024]

    int iw = i0 + wave * 2;               // this wave's first row

    // ---- phase A: scores ----
    float4 q0 = *(const float4*)(mq + (size_t)(b * Ss + iw) * AHc + h * Dd + c * 4);
    float4 q1 = *(const float4*)(mq + (size_t)(b * Ss + iw + 1) * AHc + h * Dd + c * 4);
    const float* kb = mk + (size_t)b * Ss * AHc + h * Dd + c * 4;
#pragma unroll 4
    for (int j0 = 0; j0 < Ss; j0 += 4) {
        int jr = j0 + g;
        float4 kv = *(const float4*)(kb + (size_t)jr * AHc);
        float p0 = q0.x * kv.x + q0.y * kv.y + q0.z * kv.z + q0.w * kv.w;
        float p1 = q1.x * kv.x + q1.y * kv.y + q1.z * kv.z + q1.w * kv.w;
        p0 += __shfl_xor(p0, 1); p1 += __shfl_xor(p1, 1);
        p0 += __shfl_xor(p0, 2); p1 += __shfl_xor(p1, 2);
        p0 += __shfl_xor(p0, 4); p1 += __shfl_xor(p1, 4);
        p0 += __shfl_xor(p0, 8); p1 += __shfl_xor(p1, 8);
        if (c == 0) {
            srow[wave][0][lds_idx(jr)] = p0 * 0.125f;
            srow[wave][1][lds_idx(jr)] = p1 * 0.125f;
        }
    }
    __syncthreads();

    // ---- phase B: softmax -> cumsum -> decay -> softmax2 (per row, in registers) ----
    const int* mrow = mask + b * Ss;
    const float* tdrow = td_sm + b * Ss;
    float gamma = -log1pf(expf(gammas[h]));   // -softplus
    int jb = lane << 4;                        // this lane's 16 contiguous j
    int marr[16];
    {
        const int4* mp = (const int4*)(mrow + jb);
#pragma unroll
        for (int k = 0; k < 4; ++k) ((int4*)marr)[k] = mp[k];
    }
    float tdv[16];
    {
        const float4* tp = (const float4*)(tdrow + jb);
#pragma unroll
        for (int k = 0; k < 4; ++k) ((float4*)tdv)[k] = tp[k];
    }

#pragma unroll
    for (int r = 0; r < 2; ++r) {
        int i = iw + r;
        int lbase = lane * 17;
        float s[16], p[16];
#pragma unroll
        for (int jj = 0; jj < 16; ++jj) s[jj] = srow[wave][r][lbase + jj];
        // masked max
        float mx = -1e30f;
#pragma unroll
        for (int jj = 0; jj < 16; ++jj) mx = fmaxf(mx, marr[jj] ? s[jj] : -1e30f);
        mx = fmaxf(mx, __shfl_xor(mx, 1));  mx = fmaxf(mx, __shfl_xor(mx, 2));
        mx = fmaxf(mx, __shfl_xor(mx, 4));  mx = fmaxf(mx, __shfl_xor(mx, 8));
        mx = fmaxf(mx, __shfl_xor(mx, 16)); mx = fmaxf(mx, __shfl_xor(mx, 32));
        // exp
#pragma unroll
        for (int jj = 0; jj < 16; ++jj) p[jj] = marr[jj] ? expf(s[jj] - mx) : 0.f;
        // local inclusive scan
#pragma unroll
        for (int jj = 1; jj < 16; ++jj) p[jj] += p[jj - 1];
        // wave scan of chunk totals
        float t = p[15];
        float incl = t;
#pragma unroll
        for (int d = 1; d < 64; d <<= 1) {
            float v = __shfl_up(incl, d);
            if (lane >= d) incl += v;
        }
        float off = incl - t;
        float tot = __shfl(incl, 63);
        float inv = 1.f / fmaxf(tot, 1e-30f);
        // decayed scores
        float mx2 = -1e30f;
#pragma unroll
        for (int jj = 0; jj < 16; ++jj) {
            int j = jb + jj;
            float cum = p[jj] + off;
            float pos = fabsf((float)(j - i));
            float ds = sqrtf(fmaxf((tot - cum) * inv * pos, 0.f));
            float te = fminf(fmaxf(expf(ds * gamma), 1e-5f), 1e5f);
            float mult = te - ((j < i) ? tdv[jj] : 0.f);
            float s2 = marr[jj] ? s[jj] * mult : -1e8f;
            s[jj] = s2;
            mx2 = fmaxf(mx2, s2);
        }
        mx2 = fmaxf(mx2, __shfl_xor(mx2, 1));  mx2 = fmaxf(mx2, __shfl_xor(mx2, 2));
        mx2 = fmaxf(mx2, __shfl_xor(mx2, 4));  mx2 = fmaxf(mx2, __shfl_xor(mx2, 8));
        mx2 = fmaxf(mx2, __shfl_xor(mx2, 16)); mx2 = fmaxf(mx2, __shfl_xor(mx2, 32));
        float sm = 0.f;
#pragma unroll
        for (int jj = 0; jj < 16; ++jj) { s[jj] = expf(s[jj] - mx2); sm += s[jj]; }
        sm += __shfl_xor(sm, 1);  sm += __shfl_xor(sm, 2);
        sm += __shfl_xor(sm, 4);  sm += __shfl_xor(sm, 8);
        sm += __shfl_xor(sm, 16); sm += __shfl_xor(sm, 32);
        float inv2 = 1.f / sm;
#pragma unroll
        for (int jj = 0; jj < 16; ++jj) srow[wave][r][lbase + jj] = s[jj] * inv2;
    }
    __syncthreads();

    // ---- phase C: PV ----
    const float* vb = mv + (size_t)b * Ss * AHc + h * Dd + c * 4;
    const float* pr0 = &srow[wave][0][0];
    const float* pr1 = &srow[wave][1][0];
    float4 a0 = {0, 0, 0, 0}, a1 = {0, 0, 0, 0};
#pragma unroll 4
    for (int j0 = 0; j0 < Ss; j0 += 4) {
        int jr = j0 + g;
        float4 vv = *(const float4*)(vb + (size_t)jr * AHc);
        int li = lds_idx(jr);
        float w0 = pr0[li], w1 = pr1[li];
        a0.x += w0 * vv.x; a0.y += w0 * vv.y; a0.z += w0 * vv.z; a0.w += w0 * vv.w;
        a1.x += w1 * vv.x; a1.y += w1 * vv.y; a1.z += w1 * vv.z; a1.w += w1 * vv.w;
    }
    // reduce across the 4 g-groups
#pragma unroll
    for (int m = 16; m <= 32; m <<= 1) {
        a0.x += __shfl_xor(a0.x, m); a0.y += __shfl_xor(a0.y, m);
        a0.z += __shfl_xor(a0.z, m); a0.w += __shfl_xor(a0.w, m);
        a1.x += __shfl_xor(a1.x, m); a1.y += __shfl_xor(a1.y, m);
        a1.z += __shfl_xor(a1.z, m); a1.w += __shfl_xor(a1.w, m);
    }
    if (g == 0) {
        *(float4*)(out + (size_t)(b * Ss + iw) * (2 * AHc) + h * Dd + c * 4) = a0;
        *(float4*)(out + (size_t)(b * Ss + iw + 1) * (2 * AHc) + h * Dd + c * 4) = a1;
    }
}

extern "C" void kernel_launch(void* const* d_in, const int* in_sizes, int n_in,
                              void* d_out, int out_size, void* d_ws, size_t ws_size,
                              hipStream_t stream) {
    const float* Q    = (const float*)d_in[0];
    const float* Kin  = (const float*)d_in[1];
    const float* V    = (const float*)d_in[2];
    const float* td   = (const float*)d_in[3];
    const int*   mask = (const int*)d_in[4];
    const float* Wq   = (const float*)d_in[5];
    const float* Wk   = (const float*)d_in[6];
    const float* Wv   = (const float*)d_in[7];
    const float* dww  = (const float*)d_in[8];
    const float* pww  = (const float*)d_in[9];
    const float* sepb = (const float*)d_in[10];
    const float* ckW  = (const float*)d_in[11];
    const float* ckb  = (const float*)d_in[12];
    const float* coW  = (const float*)d_in[13];
    const float* cob  = (const float*)d_in[14];
    const float* gam  = (const float*)d_in[15];
    float* out = (float*)d_out;
    float* ws = (float*)d_ws;

    const int MR = Bb * Ss;                       // 4096 rows
    float* mq    = ws;                            // MR*AH
    float* mk    = mq    + (size_t)MR * AHc;      // MR*AH
    float* mv    = mk    + (size_t)MR * AHc;      // MR*AH
    float* co    = mv    + (size_t)MR * AHc;      // MR*AH
    float* mkc   = co    + (size_t)MR * AHc;      // MR*AH
    float* dwseq = mkc   + (size_t)MR * AHc;      // MR*HID
    float* pwT   = dwseq + (size_t)MR * HIDC;     // HID*AH
    float* cksm  = pwT   + (size_t)HIDC * AHc;    // MR*H*KS
    float* tdsm  = cksm  + (size_t)MR * Hh * KSc; // B*S

    k_transpose_pw<<<(HIDC * AHc + 255) / 256, 256, 0, stream>>>(pww, pwT);
    k_depthwise<<<(MR * HIDC + 255) / 256, 256, 0, stream>>>(Kin, dww, dwseq);

    dim3 g1(AHc / 64, MR / 64);
    k_gemm<<<g1, 256, 0, stream>>>(dwseq, pwT, sepb, mkc, MR, AHc, HIDC);
    k_gemm<<<g1, 256, 0, stream>>>(Q,   Wq,  nullptr, mq, MR, AHc, HIDC);
    k_gemm<<<g1, 256, 0, stream>>>(Kin, Wk,  nullptr, mk, MR, AHc, HIDC);
    k_gemm<<<g1, 256, 0, stream>>>(V,   Wv,  nullptr, mv, MR, AHc, HIDC);
    k_gemm<<<g1, 256, 0, stream>>>(V,   coW, cob,     co, MR, AHc, HIDC);

    k_ck<<<MR, 64, 0, stream>>>(mkc, mq, ckW, ckb, cksm);
    k_convout<<<(MR * AHc + 255) / 256, 256, 0, stream>>>(co, cksm, out);
    k_td<<<Bb, 256, 0, stream>>>(td, mask, tdsm);
    k_attn<<<Bb * Hh * Ss / 8, 256, 0, stream>>>(mq, mk, mv, mask, tdsm, gam, out);
}

// Round 4
// 717.150 us; speedup vs baseline: 3.9684x; 1.3607x over previous
//
#include <hip/hip_runtime.h>
#include <hip/hip_bf16.h>

#define HIDC 768
#define Hh   6
#define Dd   64
#define AHc  384
#define KSc  9
#define PADc 4
#define Bb   4
#define Ss   1024
#define MRr  (Bb * Ss)          // 4096

typedef __attribute__((ext_vector_type(8))) __bf16 bf16x8;
typedef __attribute__((ext_vector_type(4))) float  f32x4;

// ---------------- depthwise conv over sequence: dwseq[b,s,c] (f32) ----------------
__global__ void k_depthwise(const float* __restrict__ Kin, const float* __restrict__ dww,
                            float* __restrict__ dwseq) {
    int idx = blockIdx.x * 256 + threadIdx.x;      // over B*S*HID
    if (idx >= Bb * Ss * HIDC) return;
    int c = idx % HIDC;
    int s = (idx / HIDC) % Ss;
    int b = idx / (HIDC * Ss);
    float acc = 0.f;
#pragma unroll
    for (int k = 0; k < KSc; ++k) {
        int sp = s + k - PADc;
        if (sp >= 0 && sp < Ss)
            acc += Kin[(b * Ss + sp) * HIDC + c] * dww[c * KSc + k];
    }
    dwseq[idx] = acc;
}

// ---------------- weight transpose + bf16 hi/lo split into d_out scratch ----------------
// layout: Whi[z][n][k], Wlo[z][n][k] (ushort-sized), z in {Wq,Wk,Wv,coW,pw}
__global__ void k_wsplit(const float* __restrict__ Wq, const float* __restrict__ Wk,
                         const float* __restrict__ Wv, const float* __restrict__ coW,
                         const float* __restrict__ pww,
                         __bf16* __restrict__ Whi, __bf16* __restrict__ Wlo) {
    int idx = blockIdx.x * 256 + threadIdx.x;     // over 5*384*768
    if (idx >= 5 * AHc * HIDC) return;
    int z = idx / (AHc * HIDC);
    int rem = idx - z * (AHc * HIDC);
    float x;
    int dst;
    if (z < 4) {
        // rem = k*384 + n  (coalesced read of W[k][n]); dst = (z*384+n)*768+k
        int n = rem % AHc, k = rem / AHc;
        const float* src = (z == 0) ? Wq : (z == 1) ? Wk : (z == 2) ? Wv : coW;
        x = src[rem];
        dst = (z * AHc + n) * HIDC + k;
    } else {
        // pw_w is already [n][k]
        x = pww[rem];
        dst = z * AHc * HIDC + rem;
    }
    __bf16 h = (__bf16)x;
    Whi[dst] = h;
    Wlo[dst] = (__bf16)(x - (float)h);
}

// ---------------- bias buffer: [5][384], zeros for z<3, cob for z3, sepb for z4 ----------------
__global__ void k_bias(const float* __restrict__ cob, const float* __restrict__ sepb,
                       float* __restrict__ biasb) {
    int idx = blockIdx.x * 256 + threadIdx.x;
    if (idx >= 5 * AHc) return;
    int z = idx / AHc, n = idx % AHc;
    biasb[idx] = (z == 3) ? cob[n] : (z == 4) ? sepb[n] : 0.f;
}

// ---------------- batched MFMA GEMM: C[z] = A[z](4096x768) @ B[z](768x384) + bias[z] ----------
// 3-term bf16 split (ah*bh + ah*bl + al*bh) => f32-equivalent precision.
// Block tile 128x128, 4 waves of 64x64 (4x4 mfma_f32_16x16x32_bf16 frags).
__global__ __launch_bounds__(256) void k_gemm5(
        const float* __restrict__ Q, const float* __restrict__ Kin,
        const float* __restrict__ V, const float* __restrict__ dwseq,
        const __bf16* __restrict__ Whi, const __bf16* __restrict__ Wlo,
        const float* __restrict__ biasb, float* __restrict__ Call) {
    __shared__ __attribute__((aligned(16))) __bf16 As_hi[128 * 40];
    __shared__ __attribute__((aligned(16))) __bf16 As_lo[128 * 40];
    __shared__ __attribute__((aligned(16))) __bf16 Bs_hi[128 * 40];
    __shared__ __attribute__((aligned(16))) __bf16 Bs_lo[128 * 40];

    int z = blockIdx.z;
    const float* Asrc = (z == 0) ? Q : (z == 1) ? Kin : (z <= 3) ? V : dwseq;
    int m0 = blockIdx.y * 128, n0 = blockIdx.x * 128;
    int tid = threadIdx.x;
    int wave = tid >> 6, lane = tid & 63, quad = lane >> 4, l15 = lane & 15;

    int sr = tid >> 1;                 // staging row 0..127
    int sk = (tid & 1) * 16;           // staging k-offset {0,16}
    const float* Arow = Asrc + (size_t)(m0 + sr) * HIDC + sk;
    const __bf16* BhiRow = Whi + ((size_t)(z * AHc + n0 + sr)) * HIDC + sk;
    const __bf16* BloRow = Wlo + ((size_t)(z * AHc + n0 + sr)) * HIDC + sk;

    f32x4 acc[4][4] = {};

    for (int k0 = 0; k0 < HIDC; k0 += 32) {
        // --- stage A: f32 -> (hi,lo) bf16 ---
        const float* ap = Arow + k0;
#pragma unroll
        for (int half = 0; half < 2; ++half) {
            float4 x0 = *(const float4*)(ap + half * 8);
            float4 x1 = *(const float4*)(ap + half * 8 + 4);
            float xs[8] = {x0.x, x0.y, x0.z, x0.w, x1.x, x1.y, x1.z, x1.w};
            bf16x8 hv, lv;
#pragma unroll
            for (int e = 0; e < 8; ++e) {
                __bf16 h = (__bf16)xs[e];
                hv[e] = h;
                lv[e] = (__bf16)(xs[e] - (float)h);
            }
            *(bf16x8*)&As_hi[sr * 40 + sk + half * 8] = hv;
            *(bf16x8*)&As_lo[sr * 40 + sk + half * 8] = lv;
        }
        // --- stage B: copy pre-split weights ---
        {
            const __bf16* bh = BhiRow + k0;
            const __bf16* bl = BloRow + k0;
            *(bf16x8*)&Bs_hi[sr * 40 + sk]     = *(const bf16x8*)bh;
            *(bf16x8*)&Bs_hi[sr * 40 + sk + 8] = *(const bf16x8*)(bh + 8);
            *(bf16x8*)&Bs_lo[sr * 40 + sk]     = *(const bf16x8*)bl;
            *(bf16x8*)&Bs_lo[sr * 40 + sk + 8] = *(const bf16x8*)(bl + 8);
        }
        __syncthreads();

        int mrow = (wave >> 1) * 64 + l15;
        int nrow = (wave & 1) * 64 + l15;
        bf16x8 ah[4], al[4], bh[4], bl[4];
#pragma unroll
        for (int mt = 0; mt < 4; ++mt) {
            ah[mt] = *(bf16x8*)&As_hi[(mrow + mt * 16) * 40 + quad * 8];
            al[mt] = *(bf16x8*)&As_lo[(mrow + mt * 16) * 40 + quad * 8];
        }
#pragma unroll
        for (int nt = 0; nt < 4; ++nt) {
            bh[nt] = *(bf16x8*)&Bs_hi[(nrow + nt * 16) * 40 + quad * 8];
            bl[nt] = *(bf16x8*)&Bs_lo[(nrow + nt * 16) * 40 + quad * 8];
        }
#pragma unroll
        for (int mt = 0; mt < 4; ++mt)
#pragma unroll
            for (int nt = 0; nt < 4; ++nt) {
                acc[mt][nt] = __builtin_amdgcn_mfma_f32_16x16x32_bf16(ah[mt], bh[nt], acc[mt][nt], 0, 0, 0);
                acc[mt][nt] = __builtin_amdgcn_mfma_f32_16x16x32_bf16(ah[mt], bl[nt], acc[mt][nt], 0, 0, 0);
                acc[mt][nt] = __builtin_amdgcn_mfma_f32_16x16x32_bf16(al[mt], bh[nt], acc[mt][nt], 0, 0, 0);
            }
        __syncthreads();
    }

    // epilogue: C/D layout col=lane&15, row=quad*4+reg
    float* Cz = Call + (size_t)z * MRr * AHc;
    const float* bz = biasb + z * AHc;
#pragma unroll
    for (int nt = 0; nt < 4; ++nt) {
        int n = n0 + (wave & 1) * 64 + nt * 16 + l15;
        float bias = bz[n];
#pragma unroll
        for (int mt = 0; mt < 4; ++mt) {
#pragma unroll
            for (int r = 0; r < 4; ++r) {
                int m = m0 + (wave >> 1) * 64 + mt * 16 + quad * 4 + r;
                Cz[(size_t)m * AHc + n] = acc[mt][nt][r] + bias;
            }
        }
    }
}

// ---------------- conv_attn -> ck linear -> per-head softmax over KS ----------------
__global__ __launch_bounds__(64) void k_ck(const float* __restrict__ mkc, const float* __restrict__ mq,
                                           const float* __restrict__ ckW, const float* __restrict__ ckb,
                                           float* __restrict__ ck_sm) {
    int row = blockIdx.x;            // b*S + s
    int tid = threadIdx.x;
    __shared__ float ca[AHc];
    __shared__ float ckv[Hh * KSc];
    for (int o = tid; o < AHc; o += 64)
        ca[o] = mkc[row * AHc + o] * mq[row * AHc + o];
    __syncthreads();
    if (tid < Hh * KSc) {
        float acc = ckb[tid];
        for (int o = 0; o < AHc; ++o)
            acc += ca[o] * ckW[o * (Hh * KSc) + tid];
        ckv[tid] = acc;
    }
    __syncthreads();
    if (tid < Hh) {
        float m = -3e38f;
#pragma unroll
        for (int k = 0; k < KSc; ++k) m = fmaxf(m, ckv[tid * KSc + k]);
        float e[KSc];
        float s = 0.f;
#pragma unroll
        for (int k = 0; k < KSc; ++k) { e[k] = expf(ckv[tid * KSc + k] - m); s += e[k]; }
        float inv = 1.f / s;
#pragma unroll
        for (int k = 0; k < KSc; ++k) ck_sm[(row * Hh + tid) * KSc + k] = e[k] * inv;
    }
}

// ---------------- dynamic conv output -> out[.., AH + h*D + d] ----------------
__global__ void k_convout(const float* __restrict__ co, const float* __restrict__ ck_sm,
                          float* __restrict__ out) {
    int idx = blockIdx.x * 256 + threadIdx.x;       // over B*S*AH
    if (idx >= Bb * Ss * AHc) return;
    int d = idx & 63;
    int h = (idx >> 6) % Hh;
    int s = (idx / AHc) % Ss;
    int b = idx / (AHc * Ss);
    int row = b * Ss + s;
    float acc = 0.f;
#pragma unroll
    for (int k = 0; k < KSc; ++k) {
        int sp = s + k - PADc;
        if (sp >= 0 && sp < Ss)
            acc += co[(size_t)(b * Ss + sp) * AHc + h * Dd + d] * ck_sm[(row * Hh + h) * KSc + k];
    }
    out[(size_t)row * (2 * AHc) + AHc + h * Dd + d] = acc;
}

// ---------------- per-batch td softmax row (i/h independent) ----------------
__global__ __launch_bounds__(256) void k_td(const float* __restrict__ td, const int* __restrict__ mask,
                                            float* __restrict__ td_sm) {
    int b = blockIdx.x;
    int tid = threadIdx.x;
    __shared__ float red[256];
    __shared__ float tv[Ss];
    float ls = 0.f;
    for (int j = tid; j < Ss; j += 256) {
        float v = td[b * Ss + j];
        tv[j] = v;
        ls += v * v;
    }
    red[tid] = ls; __syncthreads();
    for (int s = 128; s > 0; s >>= 1) { if (tid < s) red[tid] += red[tid + s]; __syncthreads(); }
    float norm = fmaxf(sqrtf(red[0]), 1e-12f);
    __syncthreads();
    float lm = -3e38f;
    for (int j = tid; j < Ss; j += 256) {
        float v = mask[b * Ss + j] ? tv[j] / norm : -1e4f;
        tv[j] = v;
        lm = fmaxf(lm, v);
    }
    red[tid] = lm; __syncthreads();
    for (int s = 128; s > 0; s >>= 1) { if (tid < s) red[tid] = fmaxf(red[tid], red[tid + s]); __syncthreads(); }
    float m = red[0]; __syncthreads();
    float lsum = 0.f;
    for (int j = tid; j < Ss; j += 256) {
        float e = expf(tv[j] - m);
        tv[j] = e;
        lsum += e;
    }
    red[tid] = lsum; __syncthreads();
    for (int s = 128; s > 0; s >>= 1) { if (tid < s) red[tid] += red[tid + s]; __syncthreads(); }
    float inv = 1.f / red[0];
    __syncthreads();
    for (int j = tid; j < Ss; j += 256)
        td_sm[b * Ss + j] = tv[j] * inv;
}

// ---------------- attention: 4 waves/block, each wave owns 2 query rows ----------------
#define LROW 1088   // 64 chunks * 17 dwords
__device__ __forceinline__ int lds_idx(int j) { return (j >> 4) * 17 + (j & 15); }

__global__ __launch_bounds__(256) void k_attn(const float* __restrict__ mq, const float* __restrict__ mk,
                                              const float* __restrict__ mv, const int* __restrict__ mask,
                                              const float* __restrict__ td_sm, const float* __restrict__ gammas,
                                              float* __restrict__ out) {
    int blk = blockIdx.x;                 // 3072 blocks
    int i0 = (blk & 127) << 3;            // 8 rows per block
    int bh = blk >> 7;
    int h = bh % Hh;
    int b = bh / Hh;
    int tid = threadIdx.x;
    int wave = tid >> 6, lane = tid & 63;
    int g = lane >> 4, c = lane & 15;

    __shared__ float srow[4][2][LROW];    // [wave][row][padded 1024]

    int iw = i0 + wave * 2;               // this wave's first row

    // ---- phase A: scores ----
    float4 q0 = *(const float4*)(mq + (size_t)(b * Ss + iw) * AHc + h * Dd + c * 4);
    float4 q1 = *(const float4*)(mq + (size_t)(b * Ss + iw + 1) * AHc + h * Dd + c * 4);
    const float* kb = mk + (size_t)b * Ss * AHc + h * Dd + c * 4;
#pragma unroll 4
    for (int j0 = 0; j0 < Ss; j0 += 4) {
        int jr = j0 + g;
        float4 kv = *(const float4*)(kb + (size_t)jr * AHc);
        float p0 = q0.x * kv.x + q0.y * kv.y + q0.z * kv.z + q0.w * kv.w;
        float p1 = q1.x * kv.x + q1.y * kv.y + q1.z * kv.z + q1.w * kv.w;
        p0 += __shfl_xor(p0, 1); p1 += __shfl_xor(p1, 1);
        p0 += __shfl_xor(p0, 2); p1 += __shfl_xor(p1, 2);
        p0 += __shfl_xor(p0, 4); p1 += __shfl_xor(p1, 4);
        p0 += __shfl_xor(p0, 8); p1 += __shfl_xor(p1, 8);
        if (c == 0) {
            srow[wave][0][lds_idx(jr)] = p0 * 0.125f;
            srow[wave][1][lds_idx(jr)] = p1 * 0.125f;
        }
    }
    __syncthreads();

    // ---- phase B: softmax -> cumsum -> decay -> softmax2 (per row, in registers) ----
    const int* mrow = mask + b * Ss;
    const float* tdrow = td_sm + b * Ss;
    float gamma = -log1pf(expf(gammas[h]));   // -softplus
    int jb = lane << 4;                        // this lane's 16 contiguous j
    int marr[16];
    {
        const int4* mp = (const int4*)(mrow + jb);
#pragma unroll
        for (int k = 0; k < 4; ++k) ((int4*)marr)[k] = mp[k];
    }
    float tdv[16];
    {
        const float4* tp = (const float4*)(tdrow + jb);
#pragma unroll
        for (int k = 0; k < 4; ++k) ((float4*)tdv)[k] = tp[k];
    }

#pragma unroll
    for (int r = 0; r < 2; ++r) {
        int i = iw + r;
        int lbase = lane * 17;
        float s[16], p[16];
#pragma unroll
        for (int jj = 0; jj < 16; ++jj) s[jj] = srow[wave][r][lbase + jj];
        float mx = -1e30f;
#pragma unroll
        for (int jj = 0; jj < 16; ++jj) mx = fmaxf(mx, marr[jj] ? s[jj] : -1e30f);
        mx = fmaxf(mx, __shfl_xor(mx, 1));  mx = fmaxf(mx, __shfl_xor(mx, 2));
        mx = fmaxf(mx, __shfl_xor(mx, 4));  mx = fmaxf(mx, __shfl_xor(mx, 8));
        mx = fmaxf(mx, __shfl_xor(mx, 16)); mx = fmaxf(mx, __shfl_xor(mx, 32));
#pragma unroll
        for (int jj = 0; jj < 16; ++jj) p[jj] = marr[jj] ? expf(s[jj] - mx) : 0.f;
#pragma unroll
        for (int jj = 1; jj < 16; ++jj) p[jj] += p[jj - 1];
        float t = p[15];
        float incl = t;
#pragma unroll
        for (int d = 1; d < 64; d <<= 1) {
            float v = __shfl_up(incl, d);
            if (lane >= d) incl += v;
        }
        float off = incl - t;
        float tot = __shfl(incl, 63);
        float inv = 1.f / fmaxf(tot, 1e-30f);
        float mx2 = -1e30f;
#pragma unroll
        for (int jj = 0; jj < 16; ++jj) {
            int j = jb + jj;
            float cum = p[jj] + off;
            float pos = fabsf((float)(j - i));
            float ds = sqrtf(fmaxf((tot - cum) * inv * pos, 0.f));
            float te = fminf(fmaxf(expf(ds * gamma), 1e-5f), 1e5f);
            float mult = te - ((j < i) ? tdv[jj] : 0.f);
            float s2 = marr[jj] ? s[jj] * mult : -1e8f;
            s[jj] = s2;
            mx2 = fmaxf(mx2, s2);
        }
        mx2 = fmaxf(mx2, __shfl_xor(mx2, 1));  mx2 = fmaxf(mx2, __shfl_xor(mx2, 2));
        mx2 = fmaxf(mx2, __shfl_xor(mx2, 4));  mx2 = fmaxf(mx2, __shfl_xor(mx2, 8));
        mx2 = fmaxf(mx2, __shfl_xor(mx2, 16)); mx2 = fmaxf(mx2, __shfl_xor(mx2, 32));
        float sm = 0.f;
#pragma unroll
        for (int jj = 0; jj < 16; ++jj) { s[jj] = expf(s[jj] - mx2); sm += s[jj]; }
        sm += __shfl_xor(sm, 1);  sm += __shfl_xor(sm, 2);
        sm += __shfl_xor(sm, 4);  sm += __shfl_xor(sm, 8);
        sm += __shfl_xor(sm, 16); sm += __shfl_xor(sm, 32);
        float inv2 = 1.f / sm;
#pragma unroll
        for (int jj = 0; jj < 16; ++jj) srow[wave][r][lbase + jj] = s[jj] * inv2;
    }
    __syncthreads();

    // ---- phase C: PV ----
    const float* vb = mv + (size_t)b * Ss * AHc + h * Dd + c * 4;
    const float* pr0 = &srow[wave][0][0];
    const float* pr1 = &srow[wave][1][0];
    float4 a0 = {0, 0, 0, 0}, a1 = {0, 0, 0, 0};
#pragma unroll 4
    for (int j0 = 0; j0 < Ss; j0 += 4) {
        int jr = j0 + g;
        float4 vv = *(const float4*)(vb + (size_t)jr * AHc);
        int li = lds_idx(jr);
        float w0 = pr0[li], w1 = pr1[li];
        a0.x += w0 * vv.x; a0.y += w0 * vv.y; a0.z += w0 * vv.z; a0.w += w0 * vv.w;
        a1.x += w1 * vv.x; a1.y += w1 * vv.y; a1.z += w1 * vv.z; a1.w += w1 * vv.w;
    }
#pragma unroll
    for (int m = 16; m <= 32; m <<= 1) {
        a0.x += __shfl_xor(a0.x, m); a0.y += __shfl_xor(a0.y, m);
        a0.z += __shfl_xor(a0.z, m); a0.w += __shfl_xor(a0.w, m);
        a1.x += __shfl_xor(a1.x, m); a1.y += __shfl_xor(a1.y, m);
        a1.z += __shfl_xor(a1.z, m); a1.w += __shfl_xor(a1.w, m);
    }
    if (g == 0) {
        *(float4*)(out + (size_t)(b * Ss + iw) * (2 * AHc) + h * Dd + c * 4) = a0;
        *(float4*)(out + (size_t)(b * Ss + iw + 1) * (2 * AHc) + h * Dd + c * 4) = a1;
    }
}

extern "C" void kernel_launch(void* const* d_in, const int* in_sizes, int n_in,
                              void* d_out, int out_size, void* d_ws, size_t ws_size,
                              hipStream_t stream) {
    const float* Q    = (const float*)d_in[0];
    const float* Kin  = (const float*)d_in[1];
    const float* V    = (const float*)d_in[2];
    const float* td   = (const float*)d_in[3];
    const int*   mask = (const int*)d_in[4];
    const float* Wq   = (const float*)d_in[5];
    const float* Wk   = (const float*)d_in[6];
    const float* Wv   = (const float*)d_in[7];
    const float* dww  = (const float*)d_in[8];
    const float* pww  = (const float*)d_in[9];
    const float* sepb = (const float*)d_in[10];
    const float* ckW  = (const float*)d_in[11];
    const float* ckb  = (const float*)d_in[12];
    const float* coW  = (const float*)d_in[13];
    const float* cob  = (const float*)d_in[14];
    const float* gam  = (const float*)d_in[15];
    float* out = (float*)d_out;
    float* ws = (float*)d_ws;

    // ws layout (f32), total ~45 MB
    float* mq    = ws;                              // z=0 C
    float* mk    = mq    + (size_t)MRr * AHc;       // z=1
    float* mv    = mk    + (size_t)MRr * AHc;       // z=2
    float* co    = mv    + (size_t)MRr * AHc;       // z=3
    float* mkc   = co    + (size_t)MRr * AHc;       // z=4
    float* dwseq = mkc   + (size_t)MRr * AHc;       // MR*HID f32
    float* cksm  = dwseq + (size_t)MRr * HIDC;      // MR*H*KS
    float* tdsm  = cksm  + (size_t)MRr * Hh * KSc;  // B*S
    float* biasb = tdsm  + (size_t)Bb * Ss;         // 5*384

    // d_out doubles as scratch for the split weights (5.9 MB of 12.6 MB);
    // it is fully overwritten later by k_convout + k_attn.
    __bf16* Whi = (__bf16*)d_out;
    __bf16* Wlo = Whi + (size_t)5 * AHc * HIDC;

    k_wsplit<<<(5 * AHc * HIDC + 255) / 256, 256, 0, stream>>>(Wq, Wk, Wv, coW, pww, Whi, Wlo);
    k_depthwise<<<(MRr * HIDC + 255) / 256, 256, 0, stream>>>(Kin, dww, dwseq);
    k_bias<<<(5 * AHc + 255) / 256, 256, 0, stream>>>(cob, sepb, biasb);

    dim3 gg(AHc / 128, MRr / 128, 5);   // 3 x 32 x 5
    k_gemm5<<<gg, 256, 0, stream>>>(Q, Kin, V, dwseq, Whi, Wlo, biasb, mq);

    k_ck<<<MRr, 64, 0, stream>>>(mkc, mq, ckW, ckb, cksm);
    k_convout<<<(MRr * AHc + 255) / 256, 256, 0, stream>>>(co, cksm, out);
    k_td<<<Bb, 256, 0, stream>>>(td, mask, tdsm);
    k_attn<<<Bb * Hh * Ss / 8, 256, 0, stream>>>(mq, mk, mv, mask, tdsm, gam, out);
}

// Round 6
// 416.798 us; speedup vs baseline: 6.8281x; 1.7206x over previous
//
#include <hip/hip_runtime.h>
#include <hip/hip_bf16.h>

#define HIDC 768
#define Hh   6
#define Dd   64
#define AHc  384
#define KSc  9
#define PADc 4
#define Bb   4
#define Ss   1024
#define MRr  (Bb * Ss)          // 4096

typedef __attribute__((ext_vector_type(8))) __bf16 bf16x8;
typedef __attribute__((ext_vector_type(4))) float  f32x4;

// split 8 consecutive f32 into hi/lo bf16 fragments (3-term split => ~f32 MFMA)
__device__ __forceinline__ void split8(const float* p, bf16x8& hi, bf16x8& lo) {
    float4 x0 = *(const float4*)p;
    float4 x1 = *(const float4*)(p + 4);
    float xs[8] = {x0.x, x0.y, x0.z, x0.w, x1.x, x1.y, x1.z, x1.w};
#pragma unroll
    for (int e = 0; e < 8; ++e) {
        __bf16 hv = (__bf16)xs[e];
        hi[e] = hv;
        lo[e] = (__bf16)(xs[e] - (float)hv);
    }
}

// ---------------- depthwise conv over sequence: dwseq[b,s,c] (f32) ----------------
__global__ void k_depthwise(const float* __restrict__ Kin, const float* __restrict__ dww,
                            float* __restrict__ dwseq) {
    int idx = blockIdx.x * 256 + threadIdx.x;      // over B*S*HID
    if (idx >= Bb * Ss * HIDC) return;
    int c = idx % HIDC;
    int s = (idx / HIDC) % Ss;
    int b = idx / (HIDC * Ss);
    float acc = 0.f;
#pragma unroll
    for (int k = 0; k < KSc; ++k) {
        int sp = s + k - PADc;
        if (sp >= 0 && sp < Ss)
            acc += Kin[(b * Ss + sp) * HIDC + c] * dww[c * KSc + k];
    }
    dwseq[idx] = acc;
}

// ---------------- weight transpose + bf16 hi/lo split into d_out scratch ----------------
__global__ void k_wsplit(const float* __restrict__ Wq, const float* __restrict__ Wk,
                         const float* __restrict__ Wv, const float* __restrict__ coW,
                         const float* __restrict__ pww,
                         __bf16* __restrict__ Whi, __bf16* __restrict__ Wlo) {
    int idx = blockIdx.x * 256 + threadIdx.x;     // over 5*384*768
    if (idx >= 5 * AHc * HIDC) return;
    int z = idx / (AHc * HIDC);
    int rem = idx - z * (AHc * HIDC);
    float x;
    int dst;
    if (z < 4) {
        int n = rem % AHc, k = rem / AHc;
        const float* src = (z == 0) ? Wq : (z == 1) ? Wk : (z == 2) ? Wv : coW;
        x = src[rem];
        dst = (z * AHc + n) * HIDC + k;
    } else {
        x = pww[rem];
        dst = z * AHc * HIDC + rem;
    }
    __bf16 h = (__bf16)x;
    Whi[dst] = h;
    Wlo[dst] = (__bf16)(x - (float)h);
}

// ---------------- bias buffer: [5][384] ----------------
__global__ void k_bias(const float* __restrict__ cob, const float* __restrict__ sepb,
                       float* __restrict__ biasb) {
    int idx = blockIdx.x * 256 + threadIdx.x;
    if (idx >= 5 * AHc) return;
    int z = idx / AHc, n = idx % AHc;
    biasb[idx] = (z == 3) ? cob[n] : (z == 4) ? sepb[n] : 0.f;
}

// ---------------- batched MFMA GEMM: C[z] = A[z](4096x768) @ B[z](768x384) + bias[z] ----------
__global__ __launch_bounds__(256) void k_gemm5(
        const float* __restrict__ Q, const float* __restrict__ Kin,
        const float* __restrict__ V, const float* __restrict__ dwseq,
        const __bf16* __restrict__ Whi, const __bf16* __restrict__ Wlo,
        const float* __restrict__ biasb, float* __restrict__ Call) {
    __shared__ __attribute__((aligned(16))) __bf16 As_hi[128 * 40];
    __shared__ __attribute__((aligned(16))) __bf16 As_lo[128 * 40];
    __shared__ __attribute__((aligned(16))) __bf16 Bs_hi[128 * 40];
    __shared__ __attribute__((aligned(16))) __bf16 Bs_lo[128 * 40];

    int z = blockIdx.z;
    const float* Asrc = (z == 0) ? Q : (z == 1) ? Kin : (z <= 3) ? V : dwseq;
    int m0 = blockIdx.y * 128, n0 = blockIdx.x * 128;
    int tid = threadIdx.x;
    int wave = tid >> 6, lane = tid & 63, quad = lane >> 4, l15 = lane & 15;

    int sr = tid >> 1;
    int sk = (tid & 1) * 16;
    const float* Arow = Asrc + (size_t)(m0 + sr) * HIDC + sk;
    const __bf16* BhiRow = Whi + ((size_t)(z * AHc + n0 + sr)) * HIDC + sk;
    const __bf16* BloRow = Wlo + ((size_t)(z * AHc + n0 + sr)) * HIDC + sk;

    f32x4 acc[4][4] = {};

    for (int k0 = 0; k0 < HIDC; k0 += 32) {
        const float* ap = Arow + k0;
#pragma unroll
        for (int half = 0; half < 2; ++half) {
            bf16x8 hv, lv;
            split8(ap + half * 8, hv, lv);
            *(bf16x8*)&As_hi[sr * 40 + sk + half * 8] = hv;
            *(bf16x8*)&As_lo[sr * 40 + sk + half * 8] = lv;
        }
        {
            const __bf16* bh = BhiRow + k0;
            const __bf16* bl = BloRow + k0;
            *(bf16x8*)&Bs_hi[sr * 40 + sk]     = *(const bf16x8*)bh;
            *(bf16x8*)&Bs_hi[sr * 40 + sk + 8] = *(const bf16x8*)(bh + 8);
            *(bf16x8*)&Bs_lo[sr * 40 + sk]     = *(const bf16x8*)bl;
            *(bf16x8*)&Bs_lo[sr * 40 + sk + 8] = *(const bf16x8*)(bl + 8);
        }
        __syncthreads();

        int mrow = (wave >> 1) * 64 + l15;
        int nrow = (wave & 1) * 64 + l15;
        bf16x8 ah[4], al[4], bh[4], bl[4];
#pragma unroll
        for (int mt = 0; mt < 4; ++mt) {
            ah[mt] = *(bf16x8*)&As_hi[(mrow + mt * 16) * 40 + quad * 8];
            al[mt] = *(bf16x8*)&As_lo[(mrow + mt * 16) * 40 + quad * 8];
        }
#pragma unroll
        for (int nt = 0; nt < 4; ++nt) {
            bh[nt] = *(bf16x8*)&Bs_hi[(nrow + nt * 16) * 40 + quad * 8];
            bl[nt] = *(bf16x8*)&Bs_lo[(nrow + nt * 16) * 40 + quad * 8];
        }
#pragma unroll
        for (int mt = 0; mt < 4; ++mt)
#pragma unroll
            for (int nt = 0; nt < 4; ++nt) {
                acc[mt][nt] = __builtin_amdgcn_mfma_f32_16x16x32_bf16(ah[mt], bh[nt], acc[mt][nt], 0, 0, 0);
                acc[mt][nt] = __builtin_amdgcn_mfma_f32_16x16x32_bf16(ah[mt], bl[nt], acc[mt][nt], 0, 0, 0);
                acc[mt][nt] = __builtin_amdgcn_mfma_f32_16x16x32_bf16(al[mt], bh[nt], acc[mt][nt], 0, 0, 0);
            }
        __syncthreads();
    }

    float* Cz = Call + (size_t)z * MRr * AHc;
    const float* bz = biasb + z * AHc;
#pragma unroll
    for (int nt = 0; nt < 4; ++nt) {
        int n = n0 + (wave & 1) * 64 + nt * 16 + l15;
        float bias = bz[n];
#pragma unroll
        for (int mt = 0; mt < 4; ++mt) {
#pragma unroll
            for (int r = 0; r < 4; ++r) {
                int m = m0 + (wave >> 1) * 64 + mt * 16 + quad * 4 + r;
                Cz[(size_t)m * AHc + n] = acc[mt][nt][r] + bias;
            }
        }
    }
}

// ---------------- conv_attn -> ck linear -> per-head softmax over KS ----------------
__global__ __launch_bounds__(64) void k_ck(const float* __restrict__ mkc, const float* __restrict__ mq,
                                           const float* __restrict__ ckW, const float* __restrict__ ckb,
                                           float* __restrict__ ck_sm) {
    int row = blockIdx.x;            // b*S + s
    int tid = threadIdx.x;
    __shared__ float ca[AHc];
    __shared__ float ckv[Hh * KSc];
    for (int o = tid; o < AHc; o += 64)
        ca[o] = mkc[row * AHc + o] * mq[row * AHc + o];
    __syncthreads();
    if (tid < Hh * KSc) {
        float acc = ckb[tid];
        for (int o = 0; o < AHc; ++o)
            acc += ca[o] * ckW[o * (Hh * KSc) + tid];
        ckv[tid] = acc;
    }
    __syncthreads();
    if (tid < Hh) {
        float m = -3e38f;
#pragma unroll
        for (int k = 0; k < KSc; ++k) m = fmaxf(m, ckv[tid * KSc + k]);
        float e[KSc];
        float s = 0.f;
#pragma unroll
        for (int k = 0; k < KSc; ++k) { e[k] = expf(ckv[tid * KSc + k] - m); s += e[k]; }
        float inv = 1.f / s;
#pragma unroll
        for (int k = 0; k < KSc; ++k) ck_sm[(row * Hh + tid) * KSc + k] = e[k] * inv;
    }
}

// ---------------- dynamic conv output -> out[.., AH + h*D + d] ----------------
__global__ void k_convout(const float* __restrict__ co, const float* __restrict__ ck_sm,
                          float* __restrict__ out) {
    int idx = blockIdx.x * 256 + threadIdx.x;       // over B*S*AH
    if (idx >= Bb * Ss * AHc) return;
    int d = idx & 63;
    int h = (idx >> 6) % Hh;
    int s = (idx / AHc) % Ss;
    int b = idx / (AHc * Ss);
    int row = b * Ss + s;
    float acc = 0.f;
#pragma unroll
    for (int k = 0; k < KSc; ++k) {
        int sp = s + k - PADc;
        if (sp >= 0 && sp < Ss)
            acc += co[(size_t)(b * Ss + sp) * AHc + h * Dd + d] * ck_sm[(row * Hh + h) * KSc + k];
    }
    out[(size_t)row * (2 * AHc) + AHc + h * Dd + d] = acc;
}

// ---------------- per-batch td softmax row ----------------
__global__ __launch_bounds__(256) void k_td(const float* __restrict__ td, const int* __restrict__ mask,
                                            float* __restrict__ td_sm) {
    int b = blockIdx.x;
    int tid = threadIdx.x;
    __shared__ float red[256];
    __shared__ float tv[Ss];
    float ls = 0.f;
    for (int j = tid; j < Ss; j += 256) {
        float v = td[b * Ss + j];
        tv[j] = v;
        ls += v * v;
    }
    red[tid] = ls; __syncthreads();
    for (int s = 128; s > 0; s >>= 1) { if (tid < s) red[tid] += red[tid + s]; __syncthreads(); }
    float norm = fmaxf(sqrtf(red[0]), 1e-12f);
    __syncthreads();
    float lm = -3e38f;
    for (int j = tid; j < Ss; j += 256) {
        float v = mask[b * Ss + j] ? tv[j] / norm : -1e4f;
        tv[j] = v;
        lm = fmaxf(lm, v);
    }
    red[tid] = lm; __syncthreads();
    for (int s = 128; s > 0; s >>= 1) { if (tid < s) red[tid] = fmaxf(red[tid], red[tid + s]); __syncthreads(); }
    float m = red[0]; __syncthreads();
    float lsum = 0.f;
    for (int j = tid; j < Ss; j += 256) {
        float e = expf(tv[j] - m);
        tv[j] = e;
        lsum += e;
    }
    red[tid] = lsum; __syncthreads();
    for (int s = 128; s > 0; s >>= 1) { if (tid < s) red[tid] += red[tid + s]; __syncthreads(); }
    float inv = 1.f / red[0];
    __syncthreads();
    for (int j = tid; j < Ss; j += 256)
        td_sm[b * Ss + j] = tv[j] * inv;
}

// ---------------- attention: MFMA QK^T + wave softmax/decay + SCALAR PV ----------------
// Scores tile 16x1024 f32 in LDS (64 KB) with XOR swizzle (bijective per row):
//   sidx(m,j) = m*1024 + (j&~15) + ((j ^ (j>>6) ^ m) & 15)
__device__ __forceinline__ int sidx(int m, int j) {
    return m * 1024 + (j & ~15) + ((j ^ (j >> 6) ^ m) & 15);
}

__global__ __launch_bounds__(256) void k_attn(const float* __restrict__ mq, const float* __restrict__ mk,
                                              const float* __restrict__ mv, const int* __restrict__ mask,
                                              const float* __restrict__ td_sm, const float* __restrict__ gammas,
                                              float* __restrict__ out) {
    __shared__ float sc[16 * 1024];      // 64 KB exactly
    int i0 = blockIdx.x * 16;
    int h = blockIdx.y % Hh, b = blockIdx.y / Hh;
    int tid = threadIdx.x;
    int w = tid >> 6, lane = tid & 63, quad = lane >> 4, l15 = lane & 15;
    int jw = w * 256;                     // this wave's j-range [jw, jw+256)

    // ---- phase 1: QK^T via MFMA (3-term bf16 split) ----
    bf16x8 a_hi[2], a_lo[2];
    {
        const float* qp = mq + (size_t)(b * Ss + i0 + l15) * AHc + h * Dd + quad * 8;
        split8(qp,      a_hi[0], a_lo[0]);
        split8(qp + 32, a_hi[1], a_lo[1]);
    }
#pragma unroll 2
    for (int t = 0; t < 16; ++t) {
        int jt = jw + t * 16;
        const float* kp = mk + (size_t)(b * Ss + jt + l15) * AHc + h * Dd + quad * 8;
        f32x4 acc = {0.f, 0.f, 0.f, 0.f};
#pragma unroll
        for (int kc = 0; kc < 2; ++kc) {
            bf16x8 kh, kl;
            split8(kp + kc * 32, kh, kl);
            acc = __builtin_amdgcn_mfma_f32_16x16x32_bf16(a_hi[kc], kh, acc, 0, 0, 0);
            acc = __builtin_amdgcn_mfma_f32_16x16x32_bf16(a_hi[kc], kl, acc, 0, 0, 0);
            acc = __builtin_amdgcn_mfma_f32_16x16x32_bf16(a_lo[kc], kh, acc, 0, 0, 0);
        }
#pragma unroll
        for (int r = 0; r < 4; ++r)
            sc[sidx(quad * 4 + r, jt + l15)] = acc[r] * 0.125f;   // C: col=l15, row=quad*4+r
    }
    __syncthreads();

    // ---- phase 2: softmax -> cumsum -> decay -> softmax2, wave owns rows w*4..w*4+3 ----
    const int* mrow = mask + b * Ss;
    const float* tdrow = td_sm + b * Ss;
    float gamma = -log1pf(expf(gammas[h]));   // -softplus
    int jb = lane << 4;
    int marr[16];
    {
        const int4* mp = (const int4*)(mrow + jb);
#pragma unroll
        for (int k = 0; k < 4; ++k) ((int4*)marr)[k] = mp[k];
    }
    float tdv[16];
    {
        const float4* tp = (const float4*)(tdrow + jb);
#pragma unroll
        for (int k = 0; k < 4; ++k) ((float4*)tdv)[k] = tp[k];
    }

#pragma unroll
    for (int r4 = 0; r4 < 4; ++r4) {
        int m = w * 4 + r4;
        int i = i0 + m;
        float s[16], p[16];
#pragma unroll
        for (int jj = 0; jj < 16; ++jj) s[jj] = sc[sidx(m, jb + jj)];
        float mx = -1e30f;
#pragma unroll
        for (int jj = 0; jj < 16; ++jj) mx = fmaxf(mx, marr[jj] ? s[jj] : -1e30f);
        mx = fmaxf(mx, __shfl_xor(mx, 1));  mx = fmaxf(mx, __shfl_xor(mx, 2));
        mx = fmaxf(mx, __shfl_xor(mx, 4));  mx = fmaxf(mx, __shfl_xor(mx, 8));
        mx = fmaxf(mx, __shfl_xor(mx, 16)); mx = fmaxf(mx, __shfl_xor(mx, 32));
#pragma unroll
        for (int jj = 0; jj < 16; ++jj) p[jj] = marr[jj] ? expf(s[jj] - mx) : 0.f;
#pragma unroll
        for (int jj = 1; jj < 16; ++jj) p[jj] += p[jj - 1];
        float t = p[15];
        float incl = t;
#pragma unroll
        for (int dlt = 1; dlt < 64; dlt <<= 1) {
            float v = __shfl_up(incl, dlt);
            if (lane >= dlt) incl += v;
        }
        float off = incl - t;
        float tot = __shfl(incl, 63);
        float inv = 1.f / fmaxf(tot, 1e-30f);
        float mx2 = -1e30f;
#pragma unroll
        for (int jj = 0; jj < 16; ++jj) {
            int j = jb + jj;
            float cum = p[jj] + off;
            float pos = fabsf((float)(j - i));
            float ds = sqrtf(fmaxf((tot - cum) * inv * pos, 0.f));
            float te = fminf(fmaxf(expf(ds * gamma), 1e-5f), 1e5f);
            float mult = te - ((j < i) ? tdv[jj] : 0.f);
            float s2 = marr[jj] ? s[jj] * mult : -1e8f;
            s[jj] = s2;
            mx2 = fmaxf(mx2, s2);
        }
        mx2 = fmaxf(mx2, __shfl_xor(mx2, 1));  mx2 = fmaxf(mx2, __shfl_xor(mx2, 2));
        mx2 = fmaxf(mx2, __shfl_xor(mx2, 4));  mx2 = fmaxf(mx2, __shfl_xor(mx2, 8));
        mx2 = fmaxf(mx2, __shfl_xor(mx2, 16)); mx2 = fmaxf(mx2, __shfl_xor(mx2, 32));
        float sm = 0.f;
#pragma unroll
        for (int jj = 0; jj < 16; ++jj) { s[jj] = expf(s[jj] - mx2); sm += s[jj]; }
        sm += __shfl_xor(sm, 1);  sm += __shfl_xor(sm, 2);
        sm += __shfl_xor(sm, 4);  sm += __shfl_xor(sm, 8);
        sm += __shfl_xor(sm, 16); sm += __shfl_xor(sm, 32);
        float inv2 = 1.f / sm;
#pragma unroll
        for (int jj = 0; jj < 16; ++jj) sc[sidx(m, jb + jj)] = s[jj] * inv2;
    }
    __syncthreads();

    // ---- phase 3: scalar PV (round-3-verified pattern). Wave w owns rows 4w..4w+3,
    //      covers ALL j; lane=(g,c): g = j-subrow, c = 4-float d-chunk. ----
    int g = lane >> 4, c = lane & 15;
    const float* vb = mv + (size_t)b * Ss * AHc + h * Dd + c * 4;
    float4 a0 = {0, 0, 0, 0}, a1 = {0, 0, 0, 0}, a2 = {0, 0, 0, 0}, a3 = {0, 0, 0, 0};
    int mrow0 = w * 4;
#pragma unroll 4
    for (int j0 = 0; j0 < Ss; j0 += 4) {
        int jr = j0 + g;
        float4 vv = *(const float4*)(vb + (size_t)jr * AHc);
        float w0 = sc[sidx(mrow0 + 0, jr)];
        float w1 = sc[sidx(mrow0 + 1, jr)];
        float w2 = sc[sidx(mrow0 + 2, jr)];
        float w3 = sc[sidx(mrow0 + 3, jr)];
        a0.x += w0 * vv.x; a0.y += w0 * vv.y; a0.z += w0 * vv.z; a0.w += w0 * vv.w;
        a1.x += w1 * vv.x; a1.y += w1 * vv.y; a1.z += w1 * vv.z; a1.w += w1 * vv.w;
        a2.x += w2 * vv.x; a2.y += w2 * vv.y; a2.z += w2 * vv.z; a2.w += w2 * vv.w;
        a3.x += w3 * vv.x; a3.y += w3 * vv.y; a3.z += w3 * vv.z; a3.w += w3 * vv.w;
    }
#pragma unroll
    for (int mm = 16; mm <= 32; mm <<= 1) {
        a0.x += __shfl_xor(a0.x, mm); a0.y += __shfl_xor(a0.y, mm);
        a0.z += __shfl_xor(a0.z, mm); a0.w += __shfl_xor(a0.w, mm);
        a1.x += __shfl_xor(a1.x, mm); a1.y += __shfl_xor(a1.y, mm);
        a1.z += __shfl_xor(a1.z, mm); a1.w += __shfl_xor(a1.w, mm);
        a2.x += __shfl_xor(a2.x, mm); a2.y += __shfl_xor(a2.y, mm);
        a2.z += __shfl_xor(a2.z, mm); a2.w += __shfl_xor(a2.w, mm);
        a3.x += __shfl_xor(a3.x, mm); a3.y += __shfl_xor(a3.y, mm);
        a3.z += __shfl_xor(a3.z, mm); a3.w += __shfl_xor(a3.w, mm);
    }
    if (g == 0) {
        size_t ob = (size_t)(b * Ss + i0 + mrow0) * (2 * AHc) + h * Dd + c * 4;
        *(float4*)(out + ob)                 = a0;
        *(float4*)(out + ob + 1 * 2 * AHc)   = a1;
        *(float4*)(out + ob + 2 * 2 * AHc)   = a2;
        *(float4*)(out + ob + 3 * 2 * AHc)   = a3;
    }
}

extern "C" void kernel_launch(void* const* d_in, const int* in_sizes, int n_in,
                              void* d_out, int out_size, void* d_ws, size_t ws_size,
                              hipStream_t stream) {
    const float* Q    = (const float*)d_in[0];
    const float* Kin  = (const float*)d_in[1];
    const float* V    = (const float*)d_in[2];
    const float* td   = (const float*)d_in[3];
    const int*   mask = (const int*)d_in[4];
    const float* Wq   = (const float*)d_in[5];
    const float* Wk   = (const float*)d_in[6];
    const float* Wv   = (const float*)d_in[7];
    const float* dww  = (const float*)d_in[8];
    const float* pww  = (const float*)d_in[9];
    const float* sepb = (const float*)d_in[10];
    const float* ckW  = (const float*)d_in[11];
    const float* ckb  = (const float*)d_in[12];
    const float* coW  = (const float*)d_in[13];
    const float* cob  = (const float*)d_in[14];
    const float* gam  = (const float*)d_in[15];
    float* out = (float*)d_out;
    float* ws = (float*)d_ws;

    float* mq    = ws;                              // z=0 C
    float* mk    = mq    + (size_t)MRr * AHc;       // z=1
    float* mv    = mk    + (size_t)MRr * AHc;       // z=2
    float* co    = mv    + (size_t)MRr * AHc;       // z=3
    float* mkc   = co    + (size_t)MRr * AHc;       // z=4
    float* dwseq = mkc   + (size_t)MRr * AHc;       // MR*HID f32
    float* cksm  = dwseq + (size_t)MRr * HIDC;      // MR*H*KS
    float* tdsm  = cksm  + (size_t)MRr * Hh * KSc;  // B*S
    float* biasb = tdsm  + (size_t)Bb * Ss;         // 5*384

    // d_out doubles as scratch for split weights (consumed by k_gemm5, then overwritten)
    __bf16* Whi = (__bf16*)d_out;
    __bf16* Wlo = Whi + (size_t)5 * AHc * HIDC;

    k_wsplit<<<(5 * AHc * HIDC + 255) / 256, 256, 0, stream>>>(Wq, Wk, Wv, coW, pww, Whi, Wlo);
    k_depthwise<<<(MRr * HIDC + 255) / 256, 256, 0, stream>>>(Kin, dww, dwseq);
    k_bias<<<(5 * AHc + 255) / 256, 256, 0, stream>>>(cob, sepb, biasb);

    dim3 gg(AHc / 128, MRr / 128, 5);   // 3 x 32 x 5
    k_gemm5<<<gg, 256, 0, stream>>>(Q, Kin, V, dwseq, Whi, Wlo, biasb, mq);

    k_ck<<<MRr, 64, 0, stream>>>(mkc, mq, ckW, ckb, cksm);
    k_convout<<<(MRr * AHc + 255) / 256, 256, 0, stream>>>(co, cksm, out);
    k_td<<<Bb, 256, 0, stream>>>(td, mask, tdsm);

    dim3 ga(Ss / 16, Bb * Hh);          // 64 x 24
    k_attn<<<ga, 256, 0, stream>>>(mq, mk, mv, mask, tdsm, gam, out);
}

// Round 7
// 356.262 us; speedup vs baseline: 7.9884x; 1.1699x over previous
//
#include <hip/hip_runtime.h>
#include <hip/hip_bf16.h>

#define HIDC 768
#define Hh   6
#define Dd   64
#define AHc  384
#define KSc  9
#define PADc 4
#define Bb   4
#define Ss   1024
#define MRr  (Bb * Ss)          // 4096

typedef __attribute__((ext_vector_type(8))) __bf16 bf16x8;
typedef __attribute__((ext_vector_type(4))) float  f32x4;

// split 8 consecutive f32 into hi/lo bf16 fragments (3-term split => ~f32 MFMA)
__device__ __forceinline__ void split8(const float* p, bf16x8& hi, bf16x8& lo) {
    float4 x0 = *(const float4*)p;
    float4 x1 = *(const float4*)(p + 4);
    float xs[8] = {x0.x, x0.y, x0.z, x0.w, x1.x, x1.y, x1.z, x1.w};
#pragma unroll
    for (int e = 0; e < 8; ++e) {
        __bf16 hv = (__bf16)xs[e];
        hi[e] = hv;
        lo[e] = (__bf16)(xs[e] - (float)hv);
    }
}

__device__ __forceinline__ void split8r(const float* xs, bf16x8& hi, bf16x8& lo) {
#pragma unroll
    for (int e = 0; e < 8; ++e) {
        __bf16 hv = (__bf16)xs[e];
        hi[e] = hv;
        lo[e] = (__bf16)(xs[e] - (float)hv);
    }
}

// ---------------- depthwise conv over sequence: dwseq[b,s,c] (f32) ----------------
__global__ void k_depthwise(const float* __restrict__ Kin, const float* __restrict__ dww,
                            float* __restrict__ dwseq) {
    int idx = blockIdx.x * 256 + threadIdx.x;      // over B*S*HID
    if (idx >= Bb * Ss * HIDC) return;
    int c = idx % HIDC;
    int s = (idx / HIDC) % Ss;
    int b = idx / (HIDC * Ss);
    float acc = 0.f;
#pragma unroll
    for (int k = 0; k < KSc; ++k) {
        int sp = s + k - PADc;
        if (sp >= 0 && sp < Ss)
            acc += Kin[(b * Ss + sp) * HIDC + c] * dww[c * KSc + k];
    }
    dwseq[idx] = acc;
}

// ---------------- weight transpose + bf16 hi/lo split into d_out scratch ----------------
__global__ void k_wsplit(const float* __restrict__ Wq, const float* __restrict__ Wk,
                         const float* __restrict__ Wv, const float* __restrict__ coW,
                         const float* __restrict__ pww,
                         __bf16* __restrict__ Whi, __bf16* __restrict__ Wlo) {
    int idx = blockIdx.x * 256 + threadIdx.x;     // over 5*384*768
    if (idx >= 5 * AHc * HIDC) return;
    int z = idx / (AHc * HIDC);
    int rem = idx - z * (AHc * HIDC);
    float x;
    int dst;
    if (z < 4) {
        int n = rem % AHc, k = rem / AHc;
        const float* src = (z == 0) ? Wq : (z == 1) ? Wk : (z == 2) ? Wv : coW;
        x = src[rem];
        dst = (z * AHc + n) * HIDC + k;
    } else {
        x = pww[rem];
        dst = z * AHc * HIDC + rem;
    }
    __bf16 h = (__bf16)x;
    Whi[dst] = h;
    Wlo[dst] = (__bf16)(x - (float)h);
}

// ---------------- bias buffer: [5][384] ----------------
__global__ void k_bias(const float* __restrict__ cob, const float* __restrict__ sepb,
                       float* __restrict__ biasb) {
    int idx = blockIdx.x * 256 + threadIdx.x;
    if (idx >= 5 * AHc) return;
    int z = idx / AHc, n = idx % AHc;
    biasb[idx] = (z == 3) ? cob[n] : (z == 4) ? sepb[n] : 0.f;
}

// ---------------- batched MFMA GEMM: C[z] = A[z](4096x768) @ B[z](768x384) + bias[z] ----------
__global__ __launch_bounds__(256) void k_gemm5(
        const float* __restrict__ Q, const float* __restrict__ Kin,
        const float* __restrict__ V, const float* __restrict__ dwseq,
        const __bf16* __restrict__ Whi, const __bf16* __restrict__ Wlo,
        const float* __restrict__ biasb, float* __restrict__ Call) {
    __shared__ __attribute__((aligned(16))) __bf16 As_hi[128 * 40];
    __shared__ __attribute__((aligned(16))) __bf16 As_lo[128 * 40];
    __shared__ __attribute__((aligned(16))) __bf16 Bs_hi[128 * 40];
    __shared__ __attribute__((aligned(16))) __bf16 Bs_lo[128 * 40];

    int z = blockIdx.z;
    const float* Asrc = (z == 0) ? Q : (z == 1) ? Kin : (z <= 3) ? V : dwseq;
    int m0 = blockIdx.y * 128, n0 = blockIdx.x * 128;
    int tid = threadIdx.x;
    int wave = tid >> 6, lane = tid & 63, quad = lane >> 4, l15 = lane & 15;

    int sr = tid >> 1;
    int sk = (tid & 1) * 16;
    const float* Arow = Asrc + (size_t)(m0 + sr) * HIDC + sk;
    const __bf16* BhiRow = Whi + ((size_t)(z * AHc + n0 + sr)) * HIDC + sk;
    const __bf16* BloRow = Wlo + ((size_t)(z * AHc + n0 + sr)) * HIDC + sk;

    f32x4 acc[4][4] = {};

    for (int k0 = 0; k0 < HIDC; k0 += 32) {
        const float* ap = Arow + k0;
#pragma unroll
        for (int half = 0; half < 2; ++half) {
            bf16x8 hv, lv;
            split8(ap + half * 8, hv, lv);
            *(bf16x8*)&As_hi[sr * 40 + sk + half * 8] = hv;
            *(bf16x8*)&As_lo[sr * 40 + sk + half * 8] = lv;
        }
        {
            const __bf16* bh = BhiRow + k0;
            const __bf16* bl = BloRow + k0;
            *(bf16x8*)&Bs_hi[sr * 40 + sk]     = *(const bf16x8*)bh;
            *(bf16x8*)&Bs_hi[sr * 40 + sk + 8] = *(const bf16x8*)(bh + 8);
            *(bf16x8*)&Bs_lo[sr * 40 + sk]     = *(const bf16x8*)bl;
            *(bf16x8*)&Bs_lo[sr * 40 + sk + 8] = *(const bf16x8*)(bl + 8);
        }
        __syncthreads();

        int mrow = (wave >> 1) * 64 + l15;
        int nrow = (wave & 1) * 64 + l15;
        bf16x8 ah[4], al[4], bh[4], bl[4];
#pragma unroll
        for (int mt = 0; mt < 4; ++mt) {
            ah[mt] = *(bf16x8*)&As_hi[(mrow + mt * 16) * 40 + quad * 8];
            al[mt] = *(bf16x8*)&As_lo[(mrow + mt * 16) * 40 + quad * 8];
        }
#pragma unroll
        for (int nt = 0; nt < 4; ++nt) {
            bh[nt] = *(bf16x8*)&Bs_hi[(nrow + nt * 16) * 40 + quad * 8];
            bl[nt] = *(bf16x8*)&Bs_lo[(nrow + nt * 16) * 40 + quad * 8];
        }
#pragma unroll
        for (int mt = 0; mt < 4; ++mt)
#pragma unroll
            for (int nt = 0; nt < 4; ++nt) {
                acc[mt][nt] = __builtin_amdgcn_mfma_f32_16x16x32_bf16(ah[mt], bh[nt], acc[mt][nt], 0, 0, 0);
                acc[mt][nt] = __builtin_amdgcn_mfma_f32_16x16x32_bf16(ah[mt], bl[nt], acc[mt][nt], 0, 0, 0);
                acc[mt][nt] = __builtin_amdgcn_mfma_f32_16x16x32_bf16(al[mt], bh[nt], acc[mt][nt], 0, 0, 0);
            }
        __syncthreads();
    }

    float* Cz = Call + (size_t)z * MRr * AHc;
    const float* bz = biasb + z * AHc;
#pragma unroll
    for (int nt = 0; nt < 4; ++nt) {
        int n = n0 + (wave & 1) * 64 + nt * 16 + l15;
        float bias = bz[n];
#pragma unroll
        for (int mt = 0; mt < 4; ++mt) {
#pragma unroll
            for (int r = 0; r < 4; ++r) {
                int m = m0 + (wave >> 1) * 64 + mt * 16 + quad * 4 + r;
                Cz[(size_t)m * AHc + n] = acc[mt][nt][r] + bias;
            }
        }
    }
}

// ---------------- conv_attn -> ck linear -> per-head softmax over KS ----------------
__global__ __launch_bounds__(64) void k_ck(const float* __restrict__ mkc, const float* __restrict__ mq,
                                           const float* __restrict__ ckW, const float* __restrict__ ckb,
                                           float* __restrict__ ck_sm) {
    int row = blockIdx.x;            // b*S + s
    int tid = threadIdx.x;
    __shared__ float ca[AHc];
    __shared__ float ckv[Hh * KSc];
    for (int o = tid; o < AHc; o += 64)
        ca[o] = mkc[row * AHc + o] * mq[row * AHc + o];
    __syncthreads();
    if (tid < Hh * KSc) {
        float acc = ckb[tid];
        for (int o = 0; o < AHc; ++o)
            acc += ca[o] * ckW[o * (Hh * KSc) + tid];
        ckv[tid] = acc;
    }
    __syncthreads();
    if (tid < Hh) {
        float m = -3e38f;
#pragma unroll
        for (int k = 0; k < KSc; ++k) m = fmaxf(m, ckv[tid * KSc + k]);
        float e[KSc];
        float s = 0.f;
#pragma unroll
        for (int k = 0; k < KSc; ++k) { e[k] = expf(ckv[tid * KSc + k] - m); s += e[k]; }
        float inv = 1.f / s;
#pragma unroll
        for (int k = 0; k < KSc; ++k) ck_sm[(row * Hh + tid) * KSc + k] = e[k] * inv;
    }
}

// ---------------- dynamic conv output (float4) -> out[.., AH + h*D + d] ----------------
__global__ void k_convout(const float* __restrict__ co, const float* __restrict__ ck_sm,
                          float* __restrict__ out) {
    int idx = blockIdx.x * 256 + threadIdx.x;       // over B*S*AH/4
    if (idx >= Bb * Ss * AHc / 4) return;
    int d4 = idx & 15;                  // float4 chunk within head dim (64/4)
    int h  = (idx >> 4) % Hh;
    int s  = (idx / (AHc / 4)) % Ss;
    int b  = idx / ((AHc / 4) * Ss);
    int row = b * Ss + s;
    const float* ck = ck_sm + (size_t)(row * Hh + h) * KSc;
    float4 acc = {0.f, 0.f, 0.f, 0.f};
#pragma unroll
    for (int k = 0; k < KSc; ++k) {
        int sp = s + k - PADc;
        if (sp >= 0 && sp < Ss) {
            float4 v = *(const float4*)&co[(size_t)(b * Ss + sp) * AHc + h * Dd + d4 * 4];
            float wv = ck[k];
            acc.x += wv * v.x; acc.y += wv * v.y; acc.z += wv * v.z; acc.w += wv * v.w;
        }
    }
    *(float4*)&out[(size_t)row * (2 * AHc) + AHc + h * Dd + d4 * 4] = acc;
}

// ---------------- per-batch td softmax row ----------------
__global__ __launch_bounds__(256) void k_td(const float* __restrict__ td, const int* __restrict__ mask,
                                            float* __restrict__ td_sm) {
    int b = blockIdx.x;
    int tid = threadIdx.x;
    __shared__ float red[256];
    __shared__ float tv[Ss];
    float ls = 0.f;
    for (int j = tid; j < Ss; j += 256) {
        float v = td[b * Ss + j];
        tv[j] = v;
        ls += v * v;
    }
    red[tid] = ls; __syncthreads();
    for (int s = 128; s > 0; s >>= 1) { if (tid < s) red[tid] += red[tid + s]; __syncthreads(); }
    float norm = fmaxf(sqrtf(red[0]), 1e-12f);
    __syncthreads();
    float lm = -3e38f;
    for (int j = tid; j < Ss; j += 256) {
        float v = mask[b * Ss + j] ? tv[j] / norm : -1e4f;
        tv[j] = v;
        lm = fmaxf(lm, v);
    }
    red[tid] = lm; __syncthreads();
    for (int s = 128; s > 0; s >>= 1) { if (tid < s) red[tid] = fmaxf(red[tid], red[tid + s]); __syncthreads(); }
    float m = red[0]; __syncthreads();
    float lsum = 0.f;
    for (int j = tid; j < Ss; j += 256) {
        float e = expf(tv[j] - m);
        tv[j] = e;
        lsum += e;
    }
    red[tid] = lsum; __syncthreads();
    for (int s = 128; s > 0; s >>= 1) { if (tid < s) red[tid] += red[tid + s]; __syncthreads(); }
    float inv = 1.f / red[0];
    __syncthreads();
    for (int j = tid; j < Ss; j += 256)
        td_sm[b * Ss + j] = tv[j] * inv;
}

// ---------------- attention: MFMA QK^T + wave softmax/decay + MFMA PV (direct gather) ------
// Scores tile 16x1024 f32 in LDS (64 KB) with XOR swizzle (bijective per row):
//   sidx(m,j) = m*1024 + (j&~15) + ((j ^ (j>>6) ^ m) & 15)
__device__ __forceinline__ int sidx(int m, int j) {
    return m * 1024 + (j & ~15) + ((j ^ (j >> 6) ^ m) & 15);
}

__global__ __launch_bounds__(256) void k_attn(const float* __restrict__ mq, const float* __restrict__ mk,
                                              const float* __restrict__ mv, const int* __restrict__ mask,
                                              const float* __restrict__ td_sm, const float* __restrict__ gammas,
                                              float* __restrict__ out) {
    __shared__ float sc[16 * 1024];      // 64 KB exactly
    int i0 = blockIdx.x * 16;
    int h = blockIdx.y % Hh, b = blockIdx.y / Hh;
    int tid = threadIdx.x;
    int w = tid >> 6, lane = tid & 63, quad = lane >> 4, l15 = lane & 15;
    int jw = w * 256;                     // this wave's j-range [jw, jw+256)

    // ---- phase 1: QK^T via MFMA (3-term bf16 split) ----
    bf16x8 a_hi[2], a_lo[2];
    {
        const float* qp = mq + (size_t)(b * Ss + i0 + l15) * AHc + h * Dd + quad * 8;
        split8(qp,      a_hi[0], a_lo[0]);
        split8(qp + 32, a_hi[1], a_lo[1]);
    }
#pragma unroll 2
    for (int t = 0; t < 16; ++t) {
        int jt = jw + t * 16;
        const float* kp = mk + (size_t)(b * Ss + jt + l15) * AHc + h * Dd + quad * 8;
        f32x4 acc = {0.f, 0.f, 0.f, 0.f};
#pragma unroll
        for (int kc = 0; kc < 2; ++kc) {
            bf16x8 kh, kl;
            split8(kp + kc * 32, kh, kl);
            acc = __builtin_amdgcn_mfma_f32_16x16x32_bf16(a_hi[kc], kh, acc, 0, 0, 0);
            acc = __builtin_amdgcn_mfma_f32_16x16x32_bf16(a_hi[kc], kl, acc, 0, 0, 0);
            acc = __builtin_amdgcn_mfma_f32_16x16x32_bf16(a_lo[kc], kh, acc, 0, 0, 0);
        }
#pragma unroll
        for (int r = 0; r < 4; ++r)
            sc[sidx(quad * 4 + r, jt + l15)] = acc[r] * 0.125f;   // C: col=l15, row=quad*4+r
    }
    __syncthreads();

    // ---- phase 2: softmax -> cumsum -> decay -> softmax2, wave owns rows w*4..w*4+3 ----
    const int* mrow = mask + b * Ss;
    const float* tdrow = td_sm + b * Ss;
    float gamma = -log1pf(expf(gammas[h]));   // -softplus
    int jb = lane << 4;
    int marr[16];
    {
        const int4* mp = (const int4*)(mrow + jb);
#pragma unroll
        for (int k = 0; k < 4; ++k) ((int4*)marr)[k] = mp[k];
    }
    float tdv[16];
    {
        const float4* tp = (const float4*)(tdrow + jb);
#pragma unroll
        for (int k = 0; k < 4; ++k) ((float4*)tdv)[k] = tp[k];
    }

#pragma unroll
    for (int r4 = 0; r4 < 4; ++r4) {
        int m = w * 4 + r4;
        int i = i0 + m;
        float s[16], p[16];
#pragma unroll
        for (int jj = 0; jj < 16; ++jj) s[jj] = sc[sidx(m, jb + jj)];
        float mx = -1e30f;
#pragma unroll
        for (int jj = 0; jj < 16; ++jj) mx = fmaxf(mx, marr[jj] ? s[jj] : -1e30f);
        mx = fmaxf(mx, __shfl_xor(mx, 1));  mx = fmaxf(mx, __shfl_xor(mx, 2));
        mx = fmaxf(mx, __shfl_xor(mx, 4));  mx = fmaxf(mx, __shfl_xor(mx, 8));
        mx = fmaxf(mx, __shfl_xor(mx, 16)); mx = fmaxf(mx, __shfl_xor(mx, 32));
#pragma unroll
        for (int jj = 0; jj < 16; ++jj) p[jj] = marr[jj] ? expf(s[jj] - mx) : 0.f;
#pragma unroll
        for (int jj = 1; jj < 16; ++jj) p[jj] += p[jj - 1];
        float t = p[15];
        float incl = t;
#pragma unroll
        for (int dlt = 1; dlt < 64; dlt <<= 1) {
            float v = __shfl_up(incl, dlt);
            if (lane >= dlt) incl += v;
        }
        float off = incl - t;
        float tot = __shfl(incl, 63);
        float inv = 1.f / fmaxf(tot, 1e-30f);
        float mx2 = -1e30f;
#pragma unroll
        for (int jj = 0; jj < 16; ++jj) {
            int j = jb + jj;
            float cum = p[jj] + off;
            float pos = fabsf((float)(j - i));
            float ds = sqrtf(fmaxf((tot - cum) * inv * pos, 0.f));
            float te = fminf(fmaxf(expf(ds * gamma), 1e-5f), 1e5f);
            float mult = te - ((j < i) ? tdv[jj] : 0.f);
            float s2 = marr[jj] ? s[jj] * mult : -1e8f;
            s[jj] = s2;
            mx2 = fmaxf(mx2, s2);
        }
        mx2 = fmaxf(mx2, __shfl_xor(mx2, 1));  mx2 = fmaxf(mx2, __shfl_xor(mx2, 2));
        mx2 = fmaxf(mx2, __shfl_xor(mx2, 4));  mx2 = fmaxf(mx2, __shfl_xor(mx2, 8));
        mx2 = fmaxf(mx2, __shfl_xor(mx2, 16)); mx2 = fmaxf(mx2, __shfl_xor(mx2, 32));
        float sm = 0.f;
#pragma unroll
        for (int jj = 0; jj < 16; ++jj) { s[jj] = expf(s[jj] - mx2); sm += s[jj]; }
        sm += __shfl_xor(sm, 1);  sm += __shfl_xor(sm, 2);
        sm += __shfl_xor(sm, 4);  sm += __shfl_xor(sm, 8);
        sm += __shfl_xor(sm, 16); sm += __shfl_xor(sm, 32);
        float inv2 = 1.f / sm;
#pragma unroll
        for (int jj = 0; jj < 16; ++jj) sc[sidx(m, jb + jj)] = s[jj] * inv2;
    }
    __syncthreads();

    // ---- phase 3: PV via MFMA. A = P (LDS, split), B = V gathered direct from f32 mv ----
    // Wave w covers j in [jw, jw+256) as 8 K=32 chunks; oacc[nt] = O-partial[16 x 64].
    f32x4 oacc[4] = {};
    const float* vbase = mv + (size_t)b * Ss * AHc + h * Dd;
#pragma unroll 2
    for (int kc = 0; kc < 8; ++kc) {
        int j0 = jw + kc * 32 + quad * 8;        // this lane's 8 j indices (k = quad*8+e)
        float x[8];
#pragma unroll
        for (int jj = 0; jj < 8; ++jj) x[jj] = sc[sidx(l15, j0 + jj)];
        bf16x8 p_hi, p_lo;
        split8r(x, p_hi, p_lo);
#pragma unroll
        for (int nt = 0; nt < 4; ++nt) {
            int d = nt * 16 + l15;
            float v[8];
#pragma unroll
            for (int e = 0; e < 8; ++e) v[e] = vbase[(size_t)(j0 + e) * AHc + d];
            bf16x8 v_hi, v_lo;
            split8r(v, v_hi, v_lo);
            oacc[nt] = __builtin_amdgcn_mfma_f32_16x16x32_bf16(p_hi, v_hi, oacc[nt], 0, 0, 0);
            oacc[nt] = __builtin_amdgcn_mfma_f32_16x16x32_bf16(p_lo, v_hi, oacc[nt], 0, 0, 0);
            oacc[nt] = __builtin_amdgcn_mfma_f32_16x16x32_bf16(p_hi, v_lo, oacc[nt], 0, 0, 0);
        }
    }
    __syncthreads();                      // all waves done reading sc before reuse
    // partials: [w][m][d] in reused LDS
#pragma unroll
    for (int nt = 0; nt < 4; ++nt)
#pragma unroll
        for (int r = 0; r < 4; ++r)
            sc[w * 1024 + (quad * 4 + r) * 64 + nt * 16 + l15] = oacc[nt][r];
    __syncthreads();
    // cross-wave reduce + write ctx half of out
#pragma unroll
    for (int e = 0; e < 4; ++e) {
        int idx = e * 256 + tid;
        int m = idx >> 6, dd = idx & 63;
        float v = sc[idx] + sc[1024 + idx] + sc[2048 + idx] + sc[3072 + idx];
        out[(size_t)(b * Ss + i0 + m) * (2 * AHc) + h * Dd + dd] = v;
    }
}

extern "C" void kernel_launch(void* const* d_in, const int* in_sizes, int n_in,
                              void* d_out, int out_size, void* d_ws, size_t ws_size,
                              hipStream_t stream) {
    const float* Q    = (const float*)d_in[0];
    const float* Kin  = (const float*)d_in[1];
    const float* V    = (const float*)d_in[2];
    const float* td   = (const float*)d_in[3];
    const int*   mask = (const int*)d_in[4];
    const float* Wq   = (const float*)d_in[5];
    const float* Wk   = (const float*)d_in[6];
    const float* Wv   = (const float*)d_in[7];
    const float* dww  = (const float*)d_in[8];
    const float* pww  = (const float*)d_in[9];
    const float* sepb = (const float*)d_in[10];
    const float* ckW  = (const float*)d_in[11];
    const float* ckb  = (const float*)d_in[12];
    const float* coW  = (const float*)d_in[13];
    const float* cob  = (const float*)d_in[14];
    const float* gam  = (const float*)d_in[15];
    float* out = (float*)d_out;
    float* ws = (float*)d_ws;

    float* mq    = ws;                              // z=0 C
    float* mk    = mq    + (size_t)MRr * AHc;       // z=1
    float* mv    = mk    + (size_t)MRr * AHc;       // z=2
    float* co    = mv    + (size_t)MRr * AHc;       // z=3
    float* mkc   = co    + (size_t)MRr * AHc;       // z=4
    float* dwseq = mkc   + (size_t)MRr * AHc;       // MR*HID f32
    float* cksm  = dwseq + (size_t)MRr * HIDC;      // MR*H*KS
    float* tdsm  = cksm  + (size_t)MRr * Hh * KSc;  // B*S
    float* biasb = tdsm  + (size_t)Bb * Ss;         // 5*384

    // d_out doubles as scratch for split weights (consumed by k_gemm5, then overwritten)
    __bf16* Whi = (__bf16*)d_out;
    __bf16* Wlo = Whi + (size_t)5 * AHc * HIDC;

    k_wsplit<<<(5 * AHc * HIDC + 255) / 256, 256, 0, stream>>>(Wq, Wk, Wv, coW, pww, Whi, Wlo);
    k_depthwise<<<(MRr * HIDC + 255) / 256, 256, 0, stream>>>(Kin, dww, dwseq);
    k_bias<<<(5 * AHc + 255) / 256, 256, 0, stream>>>(cob, sepb, biasb);

    dim3 gg(AHc / 128, MRr / 128, 5);   // 3 x 32 x 5
    k_gemm5<<<gg, 256, 0, stream>>>(Q, Kin, V, dwseq, Whi, Wlo, biasb, mq);

    k_ck<<<MRr, 64, 0, stream>>>(mkc, mq, ckW, ckb, cksm);
    k_convout<<<(MRr * AHc / 4 + 255) / 256, 256, 0, stream>>>(co, cksm, out);
    k_td<<<Bb, 256, 0, stream>>>(td, mask, tdsm);

    dim3 ga(Ss / 16, Bb * Hh);          // 64 x 24
    k_attn<<<ga, 256, 0, stream>>>(mq, mk, mv, mask, tdsm, gam, out);
}

// Round 8
// 325.581 us; speedup vs baseline: 8.7412x; 1.0942x over previous
//
#include <hip/hip_runtime.h>
#include <hip/hip_bf16.h>

#define HIDC 768
#define Hh   6
#define Dd   64
#define AHc  384
#define KSc  9
#define PADc 4
#define Bb   4
#define Ss   1024
#define MRr  (Bb * Ss)          // 4096

typedef __attribute__((ext_vector_type(8))) __bf16 bf16x8;
typedef __attribute__((ext_vector_type(4))) float  f32x4;

// split 8 consecutive f32 into hi/lo bf16 fragments (3-term split => ~f32 MFMA)
__device__ __forceinline__ void split8(const float* p, bf16x8& hi, bf16x8& lo) {
    float4 x0 = *(const float4*)p;
    float4 x1 = *(const float4*)(p + 4);
    float xs[8] = {x0.x, x0.y, x0.z, x0.w, x1.x, x1.y, x1.z, x1.w};
#pragma unroll
    for (int e = 0; e < 8; ++e) {
        __bf16 hv = (__bf16)xs[e];
        hi[e] = hv;
        lo[e] = (__bf16)(xs[e] - (float)hv);
    }
}

__device__ __forceinline__ void split8r(const float* xs, bf16x8& hi, bf16x8& lo) {
#pragma unroll
    for (int e = 0; e < 8; ++e) {
        __bf16 hv = (__bf16)xs[e];
        hi[e] = hv;
        lo[e] = (__bf16)(xs[e] - (float)hv);
    }
}

// ---------------- depthwise conv over sequence (float4 over channels) ----------------
__global__ void k_depthwise(const float* __restrict__ Kin, const float* __restrict__ dww,
                            float* __restrict__ dwseq) {
    int idx = blockIdx.x * 256 + threadIdx.x;      // over B*S*HID/4
    if (idx >= Bb * Ss * HIDC / 4) return;
    int c4 = idx % (HIDC / 4);
    int s  = (idx / (HIDC / 4)) % Ss;
    int b  = idx / ((HIDC / 4) * Ss);
    int c  = c4 * 4;
    float wv[4][KSc];
#pragma unroll
    for (int j = 0; j < 4; ++j)
#pragma unroll
        for (int k = 0; k < KSc; ++k) wv[j][k] = dww[(c + j) * KSc + k];
    float4 acc = {0.f, 0.f, 0.f, 0.f};
#pragma unroll
    for (int k = 0; k < KSc; ++k) {
        int sp = s + k - PADc;
        if (sp >= 0 && sp < Ss) {
            float4 v = *(const float4*)&Kin[(size_t)(b * Ss + sp) * HIDC + c];
            acc.x += v.x * wv[0][k]; acc.y += v.y * wv[1][k];
            acc.z += v.z * wv[2][k]; acc.w += v.w * wv[3][k];
        }
    }
    *(float4*)&dwseq[(size_t)idx * 4] = acc;
}

// ---------------- transposed weight split (z=0..3): LDS-tiled, coalesced both ways -------
// src W[k][n] (768x384) -> Whi/Wlo[(z*384+n)*768 + k]
__global__ __launch_bounds__(256) void k_wsplit_t(const float* __restrict__ Wq, const float* __restrict__ Wk,
                                                  const float* __restrict__ Wv, const float* __restrict__ coW,
                                                  __bf16* __restrict__ Whi, __bf16* __restrict__ Wlo) {
    int z = blockIdx.z;
    const float* src = (z == 0) ? Wq : (z == 1) ? Wk : (z == 2) ? Wv : coW;
    int n0 = blockIdx.x * 64, k0 = blockIdx.y * 64;
    int tid = threadIdx.x;
    int r = tid >> 2, cq = tid & 3;
    __shared__ float tile[64][65];      // tile[k_local][n_local]
#pragma unroll
    for (int e = 0; e < 4; ++e) {
        float4 v = *(const float4*)&src[(size_t)(k0 + r) * AHc + n0 + cq * 16 + e * 4];
        tile[r][cq * 16 + e * 4 + 0] = v.x;
        tile[r][cq * 16 + e * 4 + 1] = v.y;
        tile[r][cq * 16 + e * 4 + 2] = v.z;
        tile[r][cq * 16 + e * 4 + 3] = v.w;
    }
    __syncthreads();
    // write: n_local = r, k range = cq*16..+15
    float x[16];
#pragma unroll
    for (int e = 0; e < 16; ++e) x[e] = tile[cq * 16 + e][r];
    bf16x8 h0, l0, h1, l1;
    split8r(x, h0, l0);
    split8r(x + 8, h1, l1);
    size_t dst = ((size_t)(z * AHc + n0 + r)) * HIDC + k0 + cq * 16;
    *(bf16x8*)(Whi + dst)     = h0;
    *(bf16x8*)(Whi + dst + 8) = h1;
    *(bf16x8*)(Wlo + dst)     = l0;
    *(bf16x8*)(Wlo + dst + 8) = l1;
}

// ---------------- pw_w split (z=4, already [n][k]): plain copy-split ----------------
__global__ void k_wsplit_c(const float* __restrict__ pww,
                           __bf16* __restrict__ Whi, __bf16* __restrict__ Wlo) {
    int idx = blockIdx.x * 256 + threadIdx.x;      // over AHc*HIDC/8
    if (idx >= AHc * HIDC / 8) return;
    bf16x8 hi, lo;
    split8(pww + (size_t)idx * 8, hi, lo);
    size_t dst = (size_t)4 * AHc * HIDC + (size_t)idx * 8;
    *(bf16x8*)(Whi + dst) = hi;
    *(bf16x8*)(Wlo + dst) = lo;
}

// ---------------- Q/K hi/lo pre-split for k_attn (overlaid on dead dwseq) ----------------
__global__ void k_qksplit(const float* __restrict__ mq, const float* __restrict__ mk,
                          __bf16* __restrict__ qh, __bf16* __restrict__ ql,
                          __bf16* __restrict__ kh, __bf16* __restrict__ kl) {
    const int n8 = MRr * AHc / 8;
    int idx = blockIdx.x * 256 + threadIdx.x;
    if (idx >= 2 * n8) return;
    bool isK = idx >= n8;
    int i8 = isK ? idx - n8 : idx;
    bf16x8 hi, lo;
    split8((isK ? mk : mq) + (size_t)i8 * 8, hi, lo);
    *(bf16x8*)((isK ? kh : qh) + (size_t)i8 * 8) = hi;
    *(bf16x8*)((isK ? kl : ql) + (size_t)i8 * 8) = lo;
}

// ---------------- bias buffer: [5][384] ----------------
__global__ void k_bias(const float* __restrict__ cob, const float* __restrict__ sepb,
                       float* __restrict__ biasb) {
    int idx = blockIdx.x * 256 + threadIdx.x;
    if (idx >= 5 * AHc) return;
    int z = idx / AHc, n = idx % AHc;
    biasb[idx] = (z == 3) ? cob[n] : (z == 4) ? sepb[n] : 0.f;
}

// ---------------- batched MFMA GEMM: C[z] = A[z](4096x768) @ B[z](768x384) + bias[z] ----------
__global__ __launch_bounds__(256) void k_gemm5(
        const float* __restrict__ Q, const float* __restrict__ Kin,
        const float* __restrict__ V, const float* __restrict__ dwseq,
        const __bf16* __restrict__ Whi, const __bf16* __restrict__ Wlo,
        const float* __restrict__ biasb, float* __restrict__ Call) {
    __shared__ __attribute__((aligned(16))) __bf16 As_hi[128 * 40];
    __shared__ __attribute__((aligned(16))) __bf16 As_lo[128 * 40];
    __shared__ __attribute__((aligned(16))) __bf16 Bs_hi[128 * 40];
    __shared__ __attribute__((aligned(16))) __bf16 Bs_lo[128 * 40];

    int z = blockIdx.z;
    const float* Asrc = (z == 0) ? Q : (z == 1) ? Kin : (z <= 3) ? V : dwseq;
    int m0 = blockIdx.y * 128, n0 = blockIdx.x * 128;
    int tid = threadIdx.x;
    int wave = tid >> 6, lane = tid & 63, quad = lane >> 4, l15 = lane & 15;

    int sr = tid >> 1;
    int sk = (tid & 1) * 16;
    const float* Arow = Asrc + (size_t)(m0 + sr) * HIDC + sk;
    const __bf16* BhiRow = Whi + ((size_t)(z * AHc + n0 + sr)) * HIDC + sk;
    const __bf16* BloRow = Wlo + ((size_t)(z * AHc + n0 + sr)) * HIDC + sk;

    f32x4 acc[4][4] = {};

    for (int k0 = 0; k0 < HIDC; k0 += 32) {
        const float* ap = Arow + k0;
#pragma unroll
        for (int half = 0; half < 2; ++half) {
            bf16x8 hv, lv;
            split8(ap + half * 8, hv, lv);
            *(bf16x8*)&As_hi[sr * 40 + sk + half * 8] = hv;
            *(bf16x8*)&As_lo[sr * 40 + sk + half * 8] = lv;
        }
        {
            const __bf16* bh = BhiRow + k0;
            const __bf16* bl = BloRow + k0;
            *(bf16x8*)&Bs_hi[sr * 40 + sk]     = *(const bf16x8*)bh;
            *(bf16x8*)&Bs_hi[sr * 40 + sk + 8] = *(const bf16x8*)(bh + 8);
            *(bf16x8*)&Bs_lo[sr * 40 + sk]     = *(const bf16x8*)bl;
            *(bf16x8*)&Bs_lo[sr * 40 + sk + 8] = *(const bf16x8*)(bl + 8);
        }
        __syncthreads();

        int mrow = (wave >> 1) * 64 + l15;
        int nrow = (wave & 1) * 64 + l15;
        bf16x8 ah[4], al[4], bh[4], bl[4];
#pragma unroll
        for (int mt = 0; mt < 4; ++mt) {
            ah[mt] = *(bf16x8*)&As_hi[(mrow + mt * 16) * 40 + quad * 8];
            al[mt] = *(bf16x8*)&As_lo[(mrow + mt * 16) * 40 + quad * 8];
        }
#pragma unroll
        for (int nt = 0; nt < 4; ++nt) {
            bh[nt] = *(bf16x8*)&Bs_hi[(nrow + nt * 16) * 40 + quad * 8];
            bl[nt] = *(bf16x8*)&Bs_lo[(nrow + nt * 16) * 40 + quad * 8];
        }
#pragma unroll
        for (int mt = 0; mt < 4; ++mt)
#pragma unroll
            for (int nt = 0; nt < 4; ++nt) {
                acc[mt][nt] = __builtin_amdgcn_mfma_f32_16x16x32_bf16(ah[mt], bh[nt], acc[mt][nt], 0, 0, 0);
                acc[mt][nt] = __builtin_amdgcn_mfma_f32_16x16x32_bf16(ah[mt], bl[nt], acc[mt][nt], 0, 0, 0);
                acc[mt][nt] = __builtin_amdgcn_mfma_f32_16x16x32_bf16(al[mt], bh[nt], acc[mt][nt], 0, 0, 0);
            }
        __syncthreads();
    }

    float* Cz = Call + (size_t)z * MRr * AHc;
    const float* bz = biasb + z * AHc;
#pragma unroll
    for (int nt = 0; nt < 4; ++nt) {
        int n = n0 + (wave & 1) * 64 + nt * 16 + l15;
        float bias = bz[n];
#pragma unroll
        for (int mt = 0; mt < 4; ++mt) {
#pragma unroll
            for (int r = 0; r < 4; ++r) {
                int m = m0 + (wave >> 1) * 64 + mt * 16 + quad * 4 + r;
                Cz[(size_t)m * AHc + n] = acc[mt][nt][r] + bias;
            }
        }
    }
}

// ---------------- conv_attn -> ck linear -> per-head softmax over KS ----------------
__global__ __launch_bounds__(64) void k_ck(const float* __restrict__ mkc, const float* __restrict__ mq,
                                           const float* __restrict__ ckW, const float* __restrict__ ckb,
                                           float* __restrict__ ck_sm) {
    int row = blockIdx.x;            // b*S + s
    int tid = threadIdx.x;
    __shared__ float ca[AHc];
    __shared__ float ckv[Hh * KSc];
    for (int o = tid; o < AHc; o += 64)
        ca[o] = mkc[row * AHc + o] * mq[row * AHc + o];
    __syncthreads();
    if (tid < Hh * KSc) {
        float acc = ckb[tid];
        for (int o = 0; o < AHc; ++o)
            acc += ca[o] * ckW[o * (Hh * KSc) + tid];
        ckv[tid] = acc;
    }
    __syncthreads();
    if (tid < Hh) {
        float m = -3e38f;
#pragma unroll
        for (int k = 0; k < KSc; ++k) m = fmaxf(m, ckv[tid * KSc + k]);
        float e[KSc];
        float s = 0.f;
#pragma unroll
        for (int k = 0; k < KSc; ++k) { e[k] = expf(ckv[tid * KSc + k] - m); s += e[k]; }
        float inv = 1.f / s;
#pragma unroll
        for (int k = 0; k < KSc; ++k) ck_sm[(row * Hh + tid) * KSc + k] = e[k] * inv;
    }
}

// ---------------- dynamic conv output (float4) -> out[.., AH + h*D + d] ----------------
__global__ void k_convout(const float* __restrict__ co, const float* __restrict__ ck_sm,
                          float* __restrict__ out) {
    int idx = blockIdx.x * 256 + threadIdx.x;       // over B*S*AH/4
    if (idx >= Bb * Ss * AHc / 4) return;
    int d4 = idx & 15;
    int h  = (idx >> 4) % Hh;
    int s  = (idx / (AHc / 4)) % Ss;
    int b  = idx / ((AHc / 4) * Ss);
    int row = b * Ss + s;
    const float* ck = ck_sm + (size_t)(row * Hh + h) * KSc;
    float4 acc = {0.f, 0.f, 0.f, 0.f};
#pragma unroll
    for (int k = 0; k < KSc; ++k) {
        int sp = s + k - PADc;
        if (sp >= 0 && sp < Ss) {
            float4 v = *(const float4*)&co[(size_t)(b * Ss + sp) * AHc + h * Dd + d4 * 4];
            float wv = ck[k];
            acc.x += wv * v.x; acc.y += wv * v.y; acc.z += wv * v.z; acc.w += wv * v.w;
        }
    }
    *(float4*)&out[(size_t)row * (2 * AHc) + AHc + h * Dd + d4 * 4] = acc;
}

// ---------------- per-batch td softmax row ----------------
__global__ __launch_bounds__(256) void k_td(const float* __restrict__ td, const int* __restrict__ mask,
                                            float* __restrict__ td_sm) {
    int b = blockIdx.x;
    int tid = threadIdx.x;
    __shared__ float red[256];
    __shared__ float tv[Ss];
    float ls = 0.f;
    for (int j = tid; j < Ss; j += 256) {
        float v = td[b * Ss + j];
        tv[j] = v;
        ls += v * v;
    }
    red[tid] = ls; __syncthreads();
    for (int s = 128; s > 0; s >>= 1) { if (tid < s) red[tid] += red[tid + s]; __syncthreads(); }
    float norm = fmaxf(sqrtf(red[0]), 1e-12f);
    __syncthreads();
    float lm = -3e38f;
    for (int j = tid; j < Ss; j += 256) {
        float v = mask[b * Ss + j] ? tv[j] / norm : -1e4f;
        tv[j] = v;
        lm = fmaxf(lm, v);
    }
    red[tid] = lm; __syncthreads();
    for (int s = 128; s > 0; s >>= 1) { if (tid < s) red[tid] = fmaxf(red[tid], red[tid + s]); __syncthreads(); }
    float m = red[0]; __syncthreads();
    float lsum = 0.f;
    for (int j = tid; j < Ss; j += 256) {
        float e = expf(tv[j] - m);
        tv[j] = e;
        lsum += e;
    }
    red[tid] = lsum; __syncthreads();
    for (int s = 128; s > 0; s >>= 1) { if (tid < s) red[tid] += red[tid + s]; __syncthreads(); }
    float inv = 1.f / red[0];
    __syncthreads();
    for (int j = tid; j < Ss; j += 256)
        td_sm[b * Ss + j] = tv[j] * inv;
}

// ---------------- attention: MFMA QK^T (pre-split Q/K) + wave softmax + MFMA PV ------
__device__ __forceinline__ int sidx(int m, int j) {
    return m * 1024 + (j & ~15) + ((j ^ (j >> 6) ^ m) & 15);
}

__global__ __launch_bounds__(256) void k_attn(const __bf16* __restrict__ qh, const __bf16* __restrict__ ql,
                                              const __bf16* __restrict__ kh, const __bf16* __restrict__ kl,
                                              const float* __restrict__ mv, const int* __restrict__ mask,
                                              const float* __restrict__ td_sm, const float* __restrict__ gammas,
                                              float* __restrict__ out) {
    __shared__ float sc[16 * 1024];      // 64 KB exactly
    int i0 = blockIdx.x * 16;
    int h = blockIdx.y % Hh, b = blockIdx.y / Hh;
    int tid = threadIdx.x;
    int w = tid >> 6, lane = tid & 63, quad = lane >> 4, l15 = lane & 15;
    int jw = w * 256;                     // this wave's j-range [jw, jw+256)

    // ---- phase 1: QK^T via MFMA (pre-split bf16 hi/lo fragments) ----
    bf16x8 a_hi[2], a_lo[2];
    {
        size_t qoff = (size_t)(b * Ss + i0 + l15) * AHc + h * Dd + quad * 8;
        a_hi[0] = *(const bf16x8*)(qh + qoff);
        a_hi[1] = *(const bf16x8*)(qh + qoff + 32);
        a_lo[0] = *(const bf16x8*)(ql + qoff);
        a_lo[1] = *(const bf16x8*)(ql + qoff + 32);
    }
#pragma unroll 2
    for (int t = 0; t < 16; ++t) {
        int jt = jw + t * 16;
        size_t koff = (size_t)(b * Ss + jt + l15) * AHc + h * Dd + quad * 8;
        f32x4 acc = {0.f, 0.f, 0.f, 0.f};
#pragma unroll
        for (int kc = 0; kc < 2; ++kc) {
            bf16x8 khv = *(const bf16x8*)(kh + koff + kc * 32);
            bf16x8 klv = *(const bf16x8*)(kl + koff + kc * 32);
            acc = __builtin_amdgcn_mfma_f32_16x16x32_bf16(a_hi[kc], khv, acc, 0, 0, 0);
            acc = __builtin_amdgcn_mfma_f32_16x16x32_bf16(a_hi[kc], klv, acc, 0, 0, 0);
            acc = __builtin_amdgcn_mfma_f32_16x16x32_bf16(a_lo[kc], khv, acc, 0, 0, 0);
        }
#pragma unroll
        for (int r = 0; r < 4; ++r)
            sc[sidx(quad * 4 + r, jt + l15)] = acc[r] * 0.125f;   // C: col=l15, row=quad*4+r
    }
    __syncthreads();

    // ---- phase 2: softmax -> cumsum -> decay -> softmax2, wave owns rows w*4..w*4+3 ----
    const int* mrow = mask + b * Ss;
    const float* tdrow = td_sm + b * Ss;
    float gamma = -log1pf(expf(gammas[h]));   // -softplus
    int jb = lane << 4;
    int marr[16];
    {
        const int4* mp = (const int4*)(mrow + jb);
#pragma unroll
        for (int k = 0; k < 4; ++k) ((int4*)marr)[k] = mp[k];
    }
    float tdv[16];
    {
        const float4* tp = (const float4*)(tdrow + jb);
#pragma unroll
        for (int k = 0; k < 4; ++k) ((float4*)tdv)[k] = tp[k];
    }

#pragma unroll
    for (int r4 = 0; r4 < 4; ++r4) {
        int m = w * 4 + r4;
        int i = i0 + m;
        float s[16], p[16];
#pragma unroll
        for (int jj = 0; jj < 16; ++jj) s[jj] = sc[sidx(m, jb + jj)];
        float mx = -1e30f;
#pragma unroll
        for (int jj = 0; jj < 16; ++jj) mx = fmaxf(mx, marr[jj] ? s[jj] : -1e30f);
        mx = fmaxf(mx, __shfl_xor(mx, 1));  mx = fmaxf(mx, __shfl_xor(mx, 2));
        mx = fmaxf(mx, __shfl_xor(mx, 4));  mx = fmaxf(mx, __shfl_xor(mx, 8));
        mx = fmaxf(mx, __shfl_xor(mx, 16)); mx = fmaxf(mx, __shfl_xor(mx, 32));
#pragma unroll
        for (int jj = 0; jj < 16; ++jj) p[jj] = marr[jj] ? __expf(s[jj] - mx) : 0.f;
#pragma unroll
        for (int jj = 1; jj < 16; ++jj) p[jj] += p[jj - 1];
        float t = p[15];
        float incl = t;
#pragma unroll
        for (int dlt = 1; dlt < 64; dlt <<= 1) {
            float v = __shfl_up(incl, dlt);
            if (lane >= dlt) incl += v;
        }
        float off = incl - t;
        float tot = __shfl(incl, 63);
        float inv = 1.f / fmaxf(tot, 1e-30f);
        float mx2 = -1e30f;
#pragma unroll
        for (int jj = 0; jj < 16; ++jj) {
            int j = jb + jj;
            float cum = p[jj] + off;
            float pos = fabsf((float)(j - i));
            float ds = sqrtf(fmaxf((tot - cum) * inv * pos, 0.f));
            float te = fminf(fmaxf(__expf(ds * gamma), 1e-5f), 1e5f);
            float mult = te - ((j < i) ? tdv[jj] : 0.f);
            float s2 = marr[jj] ? s[jj] * mult : -1e8f;
            s[jj] = s2;
            mx2 = fmaxf(mx2, s2);
        }
        mx2 = fmaxf(mx2, __shfl_xor(mx2, 1));  mx2 = fmaxf(mx2, __shfl_xor(mx2, 2));
        mx2 = fmaxf(mx2, __shfl_xor(mx2, 4));  mx2 = fmaxf(mx2, __shfl_xor(mx2, 8));
        mx2 = fmaxf(mx2, __shfl_xor(mx2, 16)); mx2 = fmaxf(mx2, __shfl_xor(mx2, 32));
        float sm = 0.f;
#pragma unroll
        for (int jj = 0; jj < 16; ++jj) { s[jj] = __expf(s[jj] - mx2); sm += s[jj]; }
        sm += __shfl_xor(sm, 1);  sm += __shfl_xor(sm, 2);
        sm += __shfl_xor(sm, 4);  sm += __shfl_xor(sm, 8);
        sm += __shfl_xor(sm, 16); sm += __shfl_xor(sm, 32);
        float inv2 = 1.f / sm;
#pragma unroll
        for (int jj = 0; jj < 16; ++jj) sc[sidx(m, jb + jj)] = s[jj] * inv2;
    }
    __syncthreads();

    // ---- phase 3: PV via MFMA. A = P (LDS, split), B = V gathered direct from f32 mv ----
    f32x4 oacc[4] = {};
    const float* vbase = mv + (size_t)b * Ss * AHc + h * Dd;
#pragma unroll 2
    for (int kc = 0; kc < 8; ++kc) {
        int j0 = jw + kc * 32 + quad * 8;        // this lane's 8 j indices (k = quad*8+e)
        float x[8];
#pragma unroll
        for (int jj = 0; jj < 8; ++jj) x[jj] = sc[sidx(l15, j0 + jj)];
        bf16x8 p_hi, p_lo;
        split8r(x, p_hi, p_lo);
#pragma unroll
        for (int nt = 0; nt < 4; ++nt) {
            int d = nt * 16 + l15;
            float v[8];
#pragma unroll
            for (int e = 0; e < 8; ++e) v[e] = vbase[(size_t)(j0 + e) * AHc + d];
            bf16x8 v_hi, v_lo;
            split8r(v, v_hi, v_lo);
            oacc[nt] = __builtin_amdgcn_mfma_f32_16x16x32_bf16(p_hi, v_hi, oacc[nt], 0, 0, 0);
            oacc[nt] = __builtin_amdgcn_mfma_f32_16x16x32_bf16(p_lo, v_hi, oacc[nt], 0, 0, 0);
            oacc[nt] = __builtin_amdgcn_mfma_f32_16x16x32_bf16(p_hi, v_lo, oacc[nt], 0, 0, 0);
        }
    }
    __syncthreads();                      // all waves done reading sc before reuse
#pragma unroll
    for (int nt = 0; nt < 4; ++nt)
#pragma unroll
        for (int r = 0; r < 4; ++r)
            sc[w * 1024 + (quad * 4 + r) * 64 + nt * 16 + l15] = oacc[nt][r];
    __syncthreads();
#pragma unroll
    for (int e = 0; e < 4; ++e) {
        int idx = e * 256 + tid;
        int m = idx >> 6, dd = idx & 63;
        float v = sc[idx] + sc[1024 + idx] + sc[2048 + idx] + sc[3072 + idx];
        out[(size_t)(b * Ss + i0 + m) * (2 * AHc) + h * Dd + dd] = v;
    }
}

extern "C" void kernel_launch(void* const* d_in, const int* in_sizes, int n_in,
                              void* d_out, int out_size, void* d_ws, size_t ws_size,
                              hipStream_t stream) {
    const float* Q    = (const float*)d_in[0];
    const float* Kin  = (const float*)d_in[1];
    const float* V    = (const float*)d_in[2];
    const float* td   = (const float*)d_in[3];
    const int*   mask = (const int*)d_in[4];
    const float* Wq   = (const float*)d_in[5];
    const float* Wk   = (const float*)d_in[6];
    const float* Wv   = (const float*)d_in[7];
    const float* dww  = (const float*)d_in[8];
    const float* pww  = (const float*)d_in[9];
    const float* sepb = (const float*)d_in[10];
    const float* ckW  = (const float*)d_in[11];
    const float* ckb  = (const float*)d_in[12];
    const float* coW  = (const float*)d_in[13];
    const float* cob  = (const float*)d_in[14];
    const float* gam  = (const float*)d_in[15];
    float* out = (float*)d_out;
    float* ws = (float*)d_ws;

    float* mq    = ws;                              // z=0 C
    float* mk    = mq    + (size_t)MRr * AHc;       // z=1
    float* mv    = mk    + (size_t)MRr * AHc;       // z=2
    float* co    = mv    + (size_t)MRr * AHc;       // z=3
    float* mkc   = co    + (size_t)MRr * AHc;       // z=4
    float* dwseq = mkc   + (size_t)MRr * AHc;       // MR*HID f32 (dead after k_gemm5)
    float* cksm  = dwseq + (size_t)MRr * HIDC;      // MR*H*KS
    float* tdsm  = cksm  + (size_t)MRr * Hh * KSc;  // B*S
    float* biasb = tdsm  + (size_t)Bb * Ss;         // 5*384

    // d_out doubles as scratch for split weights (consumed by k_gemm5, then overwritten)
    __bf16* Whi = (__bf16*)d_out;
    __bf16* Wlo = Whi + (size_t)5 * AHc * HIDC;
    // pre-split Q/K overlay the dead dwseq region: 4 * MR*AH bf16 == MR*HID f32 exactly
    __bf16* qh = (__bf16*)dwseq;
    __bf16* ql = qh + (size_t)MRr * AHc;
    __bf16* kh = ql + (size_t)MRr * AHc;
    __bf16* kl = kh + (size_t)MRr * AHc;

    dim3 gt(AHc / 64, HIDC / 64, 4);    // 6 x 12 x 4
    k_wsplit_t<<<gt, 256, 0, stream>>>(Wq, Wk, Wv, coW, Whi, Wlo);
    k_wsplit_c<<<(AHc * HIDC / 8 + 255) / 256, 256, 0, stream>>>(pww, Whi, Wlo);
    k_depthwise<<<(MRr * HIDC / 4 + 255) / 256, 256, 0, stream>>>(Kin, dww, dwseq);
    k_bias<<<(5 * AHc + 255) / 256, 256, 0, stream>>>(cob, sepb, biasb);

    dim3 gg(AHc / 128, MRr / 128, 5);   // 3 x 32 x 5
    k_gemm5<<<gg, 256, 0, stream>>>(Q, Kin, V, dwseq, Whi, Wlo, biasb, mq);

    k_qksplit<<<(2 * MRr * AHc / 8 + 255) / 256, 256, 0, stream>>>(mq, mk, qh, ql, kh, kl);
    k_ck<<<MRr, 64, 0, stream>>>(mkc, mq, ckW, ckb, cksm);
    k_convout<<<(MRr * AHc / 4 + 255) / 256, 256, 0, stream>>>(co, cksm, out);
    k_td<<<Bb, 256, 0, stream>>>(td, mask, tdsm);

    dim3 ga(Ss / 16, Bb * Hh);          // 64 x 24
    k_attn<<<ga, 256, 0, stream>>>(qh, ql, kh, kl, mv, mask, tdsm, gam, out);
}

// Round 9
// 301.019 us; speedup vs baseline: 9.4544x; 1.0816x over previous
//
#include <hip/hip_runtime.h>
#include <hip/hip_bf16.h>

#define HIDC 768
#define Hh   6
#define Dd   64
#define AHc  384
#define KSc  9
#define PADc 4
#define Bb   4
#define Ss   1024
#define MRr  (Bb * Ss)          // 4096

typedef __attribute__((ext_vector_type(8))) __bf16 bf16x8;
typedef __attribute__((ext_vector_type(4))) float  f32x4;

// split 8 consecutive f32 into hi/lo bf16 fragments
__device__ __forceinline__ void split8(const float* p, bf16x8& hi, bf16x8& lo) {
    float4 x0 = *(const float4*)p;
    float4 x1 = *(const float4*)(p + 4);
    float xs[8] = {x0.x, x0.y, x0.z, x0.w, x1.x, x1.y, x1.z, x1.w};
#pragma unroll
    for (int e = 0; e < 8; ++e) {
        __bf16 hv = (__bf16)xs[e];
        hi[e] = hv;
        lo[e] = (__bf16)(xs[e] - (float)hv);
    }
}

__device__ __forceinline__ void split8r(const float* xs, bf16x8& hi, bf16x8& lo) {
#pragma unroll
    for (int e = 0; e < 8; ++e) {
        __bf16 hv = (__bf16)xs[e];
        hi[e] = hv;
        lo[e] = (__bf16)(xs[e] - (float)hv);
    }
}

// convert 8 consecutive f32 to bf16 (hi only)
__device__ __forceinline__ bf16x8 cvt8(const float* p) {
    float4 x0 = *(const float4*)p;
    float4 x1 = *(const float4*)(p + 4);
    float xs[8] = {x0.x, x0.y, x0.z, x0.w, x1.x, x1.y, x1.z, x1.w};
    bf16x8 h;
#pragma unroll
    for (int e = 0; e < 8; ++e) h[e] = (__bf16)xs[e];
    return h;
}

// ---------------- depthwise conv over sequence (float4 over channels) ----------------
__global__ void k_depthwise(const float* __restrict__ Kin, const float* __restrict__ dww,
                            float* __restrict__ dwseq) {
    int idx = blockIdx.x * 256 + threadIdx.x;      // over B*S*HID/4
    if (idx >= Bb * Ss * HIDC / 4) return;
    int c4 = idx % (HIDC / 4);
    int s  = (idx / (HIDC / 4)) % Ss;
    int b  = idx / ((HIDC / 4) * Ss);
    int c  = c4 * 4;
    float wv[4][KSc];
#pragma unroll
    for (int j = 0; j < 4; ++j)
#pragma unroll
        for (int k = 0; k < KSc; ++k) wv[j][k] = dww[(c + j) * KSc + k];
    float4 acc = {0.f, 0.f, 0.f, 0.f};
#pragma unroll
    for (int k = 0; k < KSc; ++k) {
        int sp = s + k - PADc;
        if (sp >= 0 && sp < Ss) {
            float4 v = *(const float4*)&Kin[(size_t)(b * Ss + sp) * HIDC + c];
            acc.x += v.x * wv[0][k]; acc.y += v.y * wv[1][k];
            acc.z += v.z * wv[2][k]; acc.w += v.w * wv[3][k];
        }
    }
    *(float4*)&dwseq[(size_t)idx * 4] = acc;
}

// ---------------- transposed weight split (z=0..3): LDS-tiled ----------------
__global__ __launch_bounds__(256) void k_wsplit_t(const float* __restrict__ Wq, const float* __restrict__ Wk,
                                                  const float* __restrict__ Wv, const float* __restrict__ coW,
                                                  __bf16* __restrict__ Whi, __bf16* __restrict__ Wlo) {
    int z = blockIdx.z;
    const float* src = (z == 0) ? Wq : (z == 1) ? Wk : (z == 2) ? Wv : coW;
    int n0 = blockIdx.x * 64, k0 = blockIdx.y * 64;
    int tid = threadIdx.x;
    int r = tid >> 2, cq = tid & 3;
    __shared__ float tile[64][65];      // tile[k_local][n_local]
#pragma unroll
    for (int e = 0; e < 4; ++e) {
        float4 v = *(const float4*)&src[(size_t)(k0 + r) * AHc + n0 + cq * 16 + e * 4];
        tile[r][cq * 16 + e * 4 + 0] = v.x;
        tile[r][cq * 16 + e * 4 + 1] = v.y;
        tile[r][cq * 16 + e * 4 + 2] = v.z;
        tile[r][cq * 16 + e * 4 + 3] = v.w;
    }
    __syncthreads();
    float x[16];
#pragma unroll
    for (int e = 0; e < 16; ++e) x[e] = tile[cq * 16 + e][r];
    bf16x8 h0, l0, h1, l1;
    split8r(x, h0, l0);
    split8r(x + 8, h1, l1);
    size_t dst = ((size_t)(z * AHc + n0 + r)) * HIDC + k0 + cq * 16;
    *(bf16x8*)(Whi + dst)     = h0;
    *(bf16x8*)(Whi + dst + 8) = h1;
    *(bf16x8*)(Wlo + dst)     = l0;
    *(bf16x8*)(Wlo + dst + 8) = l1;
}

// ---------------- pw_w split (z=4, already [n][k]) ----------------
__global__ void k_wsplit_c(const float* __restrict__ pww,
                           __bf16* __restrict__ Whi, __bf16* __restrict__ Wlo) {
    int idx = blockIdx.x * 256 + threadIdx.x;      // over AHc*HIDC/8
    if (idx >= AHc * HIDC / 8) return;
    bf16x8 hi, lo;
    split8(pww + (size_t)idx * 8, hi, lo);
    size_t dst = (size_t)4 * AHc * HIDC + (size_t)idx * 8;
    *(bf16x8*)(Whi + dst) = hi;
    *(bf16x8*)(Wlo + dst) = lo;
}

// ---------------- Q/K/V split for k_attn: qh, kh+kl, vh (overlaid on dead dwseq) -------
__global__ void k_qkvsplit(const float* __restrict__ mq, const float* __restrict__ mk,
                           const float* __restrict__ mv,
                           __bf16* __restrict__ qh, __bf16* __restrict__ kh,
                           __bf16* __restrict__ kl, __bf16* __restrict__ vh) {
    const int n8 = MRr * AHc / 8;
    int idx = blockIdx.x * 256 + threadIdx.x;
    if (idx >= 3 * n8) return;
    int which = idx / n8, i8 = idx % n8;
    if (which == 0) {
        *(bf16x8*)(qh + (size_t)i8 * 8) = cvt8(mq + (size_t)i8 * 8);
    } else if (which == 1) {
        bf16x8 hi, lo;
        split8(mk + (size_t)i8 * 8, hi, lo);
        *(bf16x8*)(kh + (size_t)i8 * 8) = hi;
        *(bf16x8*)(kl + (size_t)i8 * 8) = lo;
    } else {
        *(bf16x8*)(vh + (size_t)i8 * 8) = cvt8(mv + (size_t)i8 * 8);
    }
}

// ---------------- bias buffer: [5][384] ----------------
__global__ void k_bias(const float* __restrict__ cob, const float* __restrict__ sepb,
                       float* __restrict__ biasb) {
    int idx = blockIdx.x * 256 + threadIdx.x;
    if (idx >= 5 * AHc) return;
    int z = idx / AHc, n = idx % AHc;
    biasb[idx] = (z == 3) ? cob[n] : (z == 4) ? sepb[n] : 0.f;
}

// ---------------- batched MFMA GEMM (2-term: ah*bh + ah*bl) ----------------
__global__ __launch_bounds__(256) void k_gemm5(
        const float* __restrict__ Q, const float* __restrict__ Kin,
        const float* __restrict__ V, const float* __restrict__ dwseq,
        const __bf16* __restrict__ Whi, const __bf16* __restrict__ Wlo,
        const float* __restrict__ biasb, float* __restrict__ Call) {
    __shared__ __attribute__((aligned(16))) __bf16 As_hi[128 * 40];
    __shared__ __attribute__((aligned(16))) __bf16 Bs_hi[128 * 40];
    __shared__ __attribute__((aligned(16))) __bf16 Bs_lo[128 * 40];

    int z = blockIdx.z;
    const float* Asrc = (z == 0) ? Q : (z == 1) ? Kin : (z <= 3) ? V : dwseq;
    int m0 = blockIdx.y * 128, n0 = blockIdx.x * 128;
    int tid = threadIdx.x;
    int wave = tid >> 6, lane = tid & 63, quad = lane >> 4, l15 = lane & 15;

    int sr = tid >> 1;
    int sk = (tid & 1) * 16;
    const float* Arow = Asrc + (size_t)(m0 + sr) * HIDC + sk;
    const __bf16* BhiRow = Whi + ((size_t)(z * AHc + n0 + sr)) * HIDC + sk;
    const __bf16* BloRow = Wlo + ((size_t)(z * AHc + n0 + sr)) * HIDC + sk;

    f32x4 acc[4][4] = {};

    for (int k0 = 0; k0 < HIDC; k0 += 32) {
        const float* ap = Arow + k0;
        *(bf16x8*)&As_hi[sr * 40 + sk]     = cvt8(ap);
        *(bf16x8*)&As_hi[sr * 40 + sk + 8] = cvt8(ap + 8);
        {
            const __bf16* bh = BhiRow + k0;
            const __bf16* bl = BloRow + k0;
            *(bf16x8*)&Bs_hi[sr * 40 + sk]     = *(const bf16x8*)bh;
            *(bf16x8*)&Bs_hi[sr * 40 + sk + 8] = *(const bf16x8*)(bh + 8);
            *(bf16x8*)&Bs_lo[sr * 40 + sk]     = *(const bf16x8*)bl;
            *(bf16x8*)&Bs_lo[sr * 40 + sk + 8] = *(const bf16x8*)(bl + 8);
        }
        __syncthreads();

        int mrow = (wave >> 1) * 64 + l15;
        int nrow = (wave & 1) * 64 + l15;
        bf16x8 ah[4], bh[4], bl[4];
#pragma unroll
        for (int mt = 0; mt < 4; ++mt)
            ah[mt] = *(bf16x8*)&As_hi[(mrow + mt * 16) * 40 + quad * 8];
#pragma unroll
        for (int nt = 0; nt < 4; ++nt) {
            bh[nt] = *(bf16x8*)&Bs_hi[(nrow + nt * 16) * 40 + quad * 8];
            bl[nt] = *(bf16x8*)&Bs_lo[(nrow + nt * 16) * 40 + quad * 8];
        }
#pragma unroll
        for (int mt = 0; mt < 4; ++mt)
#pragma unroll
            for (int nt = 0; nt < 4; ++nt) {
                acc[mt][nt] = __builtin_amdgcn_mfma_f32_16x16x32_bf16(ah[mt], bh[nt], acc[mt][nt], 0, 0, 0);
                acc[mt][nt] = __builtin_amdgcn_mfma_f32_16x16x32_bf16(ah[mt], bl[nt], acc[mt][nt], 0, 0, 0);
            }
        __syncthreads();
    }

    float* Cz = Call + (size_t)z * MRr * AHc;
    const float* bz = biasb + z * AHc;
#pragma unroll
    for (int nt = 0; nt < 4; ++nt) {
        int n = n0 + (wave & 1) * 64 + nt * 16 + l15;
        float bias = bz[n];
#pragma unroll
        for (int mt = 0; mt < 4; ++mt) {
#pragma unroll
            for (int r = 0; r < 4; ++r) {
                int m = m0 + (wave >> 1) * 64 + mt * 16 + quad * 4 + r;
                Cz[(size_t)m * AHc + n] = acc[mt][nt][r] + bias;
            }
        }
    }
}

// ---------------- conv_attn -> ck linear -> per-head softmax over KS ----------------
__global__ __launch_bounds__(64) void k_ck(const float* __restrict__ mkc, const float* __restrict__ mq,
                                           const float* __restrict__ ckW, const float* __restrict__ ckb,
                                           float* __restrict__ ck_sm) {
    int row = blockIdx.x;            // b*S + s
    int tid = threadIdx.x;
    __shared__ float ca[AHc];
    __shared__ float ckv[Hh * KSc];
    for (int o = tid; o < AHc; o += 64)
        ca[o] = mkc[row * AHc + o] * mq[row * AHc + o];
    __syncthreads();
    if (tid < Hh * KSc) {
        float acc = ckb[tid];
        for (int o = 0; o < AHc; ++o)
            acc += ca[o] * ckW[o * (Hh * KSc) + tid];
        ckv[tid] = acc;
    }
    __syncthreads();
    if (tid < Hh) {
        float m = -3e38f;
#pragma unroll
        for (int k = 0; k < KSc; ++k) m = fmaxf(m, ckv[tid * KSc + k]);
        float e[KSc];
        float s = 0.f;
#pragma unroll
        for (int k = 0; k < KSc; ++k) { e[k] = expf(ckv[tid * KSc + k] - m); s += e[k]; }
        float inv = 1.f / s;
#pragma unroll
        for (int k = 0; k < KSc; ++k) ck_sm[(row * Hh + tid) * KSc + k] = e[k] * inv;
    }
}

// ---------------- dynamic conv output (float4) -> out[.., AH + h*D + d] ----------------
__global__ void k_convout(const float* __restrict__ co, const float* __restrict__ ck_sm,
                          float* __restrict__ out) {
    int idx = blockIdx.x * 256 + threadIdx.x;       // over B*S*AH/4
    if (idx >= Bb * Ss * AHc / 4) return;
    int d4 = idx & 15;
    int h  = (idx >> 4) % Hh;
    int s  = (idx / (AHc / 4)) % Ss;
    int b  = idx / ((AHc / 4) * Ss);
    int row = b * Ss + s;
    const float* ck = ck_sm + (size_t)(row * Hh + h) * KSc;
    float4 acc = {0.f, 0.f, 0.f, 0.f};
#pragma unroll
    for (int k = 0; k < KSc; ++k) {
        int sp = s + k - PADc;
        if (sp >= 0 && sp < Ss) {
            float4 v = *(const float4*)&co[(size_t)(b * Ss + sp) * AHc + h * Dd + d4 * 4];
            float wv = ck[k];
            acc.x += wv * v.x; acc.y += wv * v.y; acc.z += wv * v.z; acc.w += wv * v.w;
        }
    }
    *(float4*)&out[(size_t)row * (2 * AHc) + AHc + h * Dd + d4 * 4] = acc;
}

// ---------------- per-batch td softmax row ----------------
__global__ __launch_bounds__(256) void k_td(const float* __restrict__ td, const int* __restrict__ mask,
                                            float* __restrict__ td_sm) {
    int b = blockIdx.x;
    int tid = threadIdx.x;
    __shared__ float red[256];
    __shared__ float tv[Ss];
    float ls = 0.f;
    for (int j = tid; j < Ss; j += 256) {
        float v = td[b * Ss + j];
        tv[j] = v;
        ls += v * v;
    }
    red[tid] = ls; __syncthreads();
    for (int s = 128; s > 0; s >>= 1) { if (tid < s) red[tid] += red[tid + s]; __syncthreads(); }
    float norm = fmaxf(sqrtf(red[0]), 1e-12f);
    __syncthreads();
    float lm = -3e38f;
    for (int j = tid; j < Ss; j += 256) {
        float v = mask[b * Ss + j] ? tv[j] / norm : -1e4f;
        tv[j] = v;
        lm = fmaxf(lm, v);
    }
    red[tid] = lm; __syncthreads();
    for (int s = 128; s > 0; s >>= 1) { if (tid < s) red[tid] = fmaxf(red[tid], red[tid + s]); __syncthreads(); }
    float m = red[0]; __syncthreads();
    float lsum = 0.f;
    for (int j = tid; j < Ss; j += 256) {
        float e = expf(tv[j] - m);
        tv[j] = e;
        lsum += e;
    }
    red[tid] = lsum; __syncthreads();
    for (int s = 128; s > 0; s >>= 1) { if (tid < s) red[tid] += red[tid + s]; __syncthreads(); }
    float inv = 1.f / red[0];
    __syncthreads();
    for (int j = tid; j < Ss; j += 256)
        td_sm[b * Ss + j] = tv[j] * inv;
}

// ---------------- attention: 2-term MFMA QK^T + wave softmax + 2-term MFMA PV ------
__device__ __forceinline__ int sidx(int m, int j) {
    return m * 1024 + (j & ~15) + ((j ^ (j >> 6) ^ m) & 15);
}

__global__ __launch_bounds__(256) void k_attn(const __bf16* __restrict__ qh,
                                              const __bf16* __restrict__ kh, const __bf16* __restrict__ kl,
                                              const __bf16* __restrict__ vh,
                                              const int* __restrict__ mask,
                                              const float* __restrict__ td_sm, const float* __restrict__ gammas,
                                              float* __restrict__ out) {
    __shared__ float sc[16 * 1024];      // 64 KB exactly
    int i0 = blockIdx.x * 16;
    int h = blockIdx.y % Hh, b = blockIdx.y / Hh;
    int tid = threadIdx.x;
    int w = tid >> 6, lane = tid & 63, quad = lane >> 4, l15 = lane & 15;
    int jw = w * 256;                     // this wave's j-range [jw, jw+256)

    // ---- phase 1: QK^T via MFMA: q_hi*(k_hi + k_lo) ----
    bf16x8 a_hi[2];
    {
        size_t qoff = (size_t)(b * Ss + i0 + l15) * AHc + h * Dd + quad * 8;
        a_hi[0] = *(const bf16x8*)(qh + qoff);
        a_hi[1] = *(const bf16x8*)(qh + qoff + 32);
    }
#pragma unroll 2
    for (int t = 0; t < 16; ++t) {
        int jt = jw + t * 16;
        size_t koff = (size_t)(b * Ss + jt + l15) * AHc + h * Dd + quad * 8;
        f32x4 acc = {0.f, 0.f, 0.f, 0.f};
#pragma unroll
        for (int kc = 0; kc < 2; ++kc) {
            bf16x8 khv = *(const bf16x8*)(kh + koff + kc * 32);
            bf16x8 klv = *(const bf16x8*)(kl + koff + kc * 32);
            acc = __builtin_amdgcn_mfma_f32_16x16x32_bf16(a_hi[kc], khv, acc, 0, 0, 0);
            acc = __builtin_amdgcn_mfma_f32_16x16x32_bf16(a_hi[kc], klv, acc, 0, 0, 0);
        }
#pragma unroll
        for (int r = 0; r < 4; ++r)
            sc[sidx(quad * 4 + r, jt + l15)] = acc[r] * 0.125f;   // C: col=l15, row=quad*4+r
    }
    __syncthreads();

    // ---- phase 2: softmax -> cumsum -> decay -> softmax2, wave owns rows w*4..w*4+3 ----
    const int* mrow = mask + b * Ss;
    const float* tdrow = td_sm + b * Ss;
    float gamma = -log1pf(expf(gammas[h]));   // -softplus
    int jb = lane << 4;
    int marr[16];
    {
        const int4* mp = (const int4*)(mrow + jb);
#pragma unroll
        for (int k = 0; k < 4; ++k) ((int4*)marr)[k] = mp[k];
    }
    float tdv[16];
    {
        const float4* tp = (const float4*)(tdrow + jb);
#pragma unroll
        for (int k = 0; k < 4; ++k) ((float4*)tdv)[k] = tp[k];
    }

#pragma unroll
    for (int r4 = 0; r4 < 4; ++r4) {
        int m = w * 4 + r4;
        int i = i0 + m;
        float s[16], p[16];
#pragma unroll
        for (int jj = 0; jj < 16; ++jj) s[jj] = sc[sidx(m, jb + jj)];
        float mx = -1e30f;
#pragma unroll
        for (int jj = 0; jj < 16; ++jj) mx = fmaxf(mx, marr[jj] ? s[jj] : -1e30f);
        mx = fmaxf(mx, __shfl_xor(mx, 1));  mx = fmaxf(mx, __shfl_xor(mx, 2));
        mx = fmaxf(mx, __shfl_xor(mx, 4));  mx = fmaxf(mx, __shfl_xor(mx, 8));
        mx = fmaxf(mx, __shfl_xor(mx, 16)); mx = fmaxf(mx, __shfl_xor(mx, 32));
#pragma unroll
        for (int jj = 0; jj < 16; ++jj) p[jj] = marr[jj] ? __expf(s[jj] - mx) : 0.f;
#pragma unroll
        for (int jj = 1; jj < 16; ++jj) p[jj] += p[jj - 1];
        float t = p[15];
        float incl = t;
#pragma unroll
        for (int dlt = 1; dlt < 64; dlt <<= 1) {
            float v = __shfl_up(incl, dlt);
            if (lane >= dlt) incl += v;
        }
        float off = incl - t;
        float tot = __shfl(incl, 63);
        float inv = 1.f / fmaxf(tot, 1e-30f);
        float mx2 = -1e30f;
#pragma unroll
        for (int jj = 0; jj < 16; ++jj) {
            int j = jb + jj;
            float cum = p[jj] + off;
            float pos = fabsf((float)(j - i));
            float ds = sqrtf(fmaxf((tot - cum) * inv * pos, 0.f));
            float te = fminf(fmaxf(__expf(ds * gamma), 1e-5f), 1e5f);
            float mult = te - ((j < i) ? tdv[jj] : 0.f);
            float s2 = marr[jj] ? s[jj] * mult : -1e8f;
            s[jj] = s2;
            mx2 = fmaxf(mx2, s2);
        }
        mx2 = fmaxf(mx2, __shfl_xor(mx2, 1));  mx2 = fmaxf(mx2, __shfl_xor(mx2, 2));
        mx2 = fmaxf(mx2, __shfl_xor(mx2, 4));  mx2 = fmaxf(mx2, __shfl_xor(mx2, 8));
        mx2 = fmaxf(mx2, __shfl_xor(mx2, 16)); mx2 = fmaxf(mx2, __shfl_xor(mx2, 32));
        float sm = 0.f;
#pragma unroll
        for (int jj = 0; jj < 16; ++jj) { s[jj] = __expf(s[jj] - mx2); sm += s[jj]; }
        sm += __shfl_xor(sm, 1);  sm += __shfl_xor(sm, 2);
        sm += __shfl_xor(sm, 4);  sm += __shfl_xor(sm, 8);
        sm += __shfl_xor(sm, 16); sm += __shfl_xor(sm, 32);
        float inv2 = 1.f / sm;
#pragma unroll
        for (int jj = 0; jj < 16; ++jj) sc[sidx(m, jb + jj)] = s[jj] * inv2;
    }
    __syncthreads();

    // ---- phase 3: PV via MFMA: (p_hi + p_lo) * v_hi; V pre-split bf16 [j][d] ----
    f32x4 oacc[4] = {};
    const __bf16* vbase = vh + (size_t)b * Ss * AHc + h * Dd;
#pragma unroll 2
    for (int kc = 0; kc < 8; ++kc) {
        int j0 = jw + kc * 32 + quad * 8;        // this lane's 8 j indices (k = quad*8+e)
        float x[8];
#pragma unroll
        for (int jj = 0; jj < 8; ++jj) x[jj] = sc[sidx(l15, j0 + jj)];
        bf16x8 p_hi, p_lo;
        split8r(x, p_hi, p_lo);
#pragma unroll
        for (int nt = 0; nt < 4; ++nt) {
            int d = nt * 16 + l15;
            bf16x8 vv;
#pragma unroll
            for (int e = 0; e < 8; ++e) vv[e] = vbase[(size_t)(j0 + e) * AHc + d];
            oacc[nt] = __builtin_amdgcn_mfma_f32_16x16x32_bf16(p_hi, vv, oacc[nt], 0, 0, 0);
            oacc[nt] = __builtin_amdgcn_mfma_f32_16x16x32_bf16(p_lo, vv, oacc[nt], 0, 0, 0);
        }
    }
    __syncthreads();                      // all waves done reading sc before reuse
#pragma unroll
    for (int nt = 0; nt < 4; ++nt)
#pragma unroll
        for (int r = 0; r < 4; ++r)
            sc[w * 1024 + (quad * 4 + r) * 64 + nt * 16 + l15] = oacc[nt][r];
    __syncthreads();
#pragma unroll
    for (int e = 0; e < 4; ++e) {
        int idx = e * 256 + tid;
        int m = idx >> 6, dd = idx & 63;
        float v = sc[idx] + sc[1024 + idx] + sc[2048 + idx] + sc[3072 + idx];
        out[(size_t)(b * Ss + i0 + m) * (2 * AHc) + h * Dd + dd] = v;
    }
}

extern "C" void kernel_launch(void* const* d_in, const int* in_sizes, int n_in,
                              void* d_out, int out_size, void* d_ws, size_t ws_size,
                              hipStream_t stream) {
    const float* Q    = (const float*)d_in[0];
    const float* Kin  = (const float*)d_in[1];
    const float* V    = (const float*)d_in[2];
    const float* td   = (const float*)d_in[3];
    const int*   mask = (const int*)d_in[4];
    const float* Wq   = (const float*)d_in[5];
    const float* Wk   = (const float*)d_in[6];
    const float* Wv   = (const float*)d_in[7];
    const float* dww  = (const float*)d_in[8];
    const float* pww  = (const float*)d_in[9];
    const float* sepb = (const float*)d_in[10];
    const float* ckW  = (const float*)d_in[11];
    const float* ckb  = (const float*)d_in[12];
    const float* coW  = (const float*)d_in[13];
    const float* cob  = (const float*)d_in[14];
    const float* gam  = (const float*)d_in[15];
    float* out = (float*)d_out;
    float* ws = (float*)d_ws;

    float* mq    = ws;                              // z=0 C
    float* mk    = mq    + (size_t)MRr * AHc;       // z=1
    float* mv    = mk    + (size_t)MRr * AHc;       // z=2
    float* co    = mv    + (size_t)MRr * AHc;       // z=3
    float* mkc   = co    + (size_t)MRr * AHc;       // z=4
    float* dwseq = mkc   + (size_t)MRr * AHc;       // MR*HID f32 (dead after k_gemm5)
    float* cksm  = dwseq + (size_t)MRr * HIDC;      // MR*H*KS
    float* tdsm  = cksm  + (size_t)MRr * Hh * KSc;  // B*S
    float* biasb = tdsm  + (size_t)Bb * Ss;         // 5*384

    // d_out doubles as scratch for split weights (consumed by k_gemm5, then overwritten)
    __bf16* Whi = (__bf16*)d_out;
    __bf16* Wlo = Whi + (size_t)5 * AHc * HIDC;
    // qh/kh/kl/vh overlay the dead dwseq region: 4 * MR*AH bf16 == MR*HID f32 exactly
    __bf16* qh = (__bf16*)dwseq;
    __bf16* kh = qh + (size_t)MRr * AHc;
    __bf16* kl = kh + (size_t)MRr * AHc;
    __bf16* vh = kl + (size_t)MRr * AHc;

    dim3 gt(AHc / 64, HIDC / 64, 4);    // 6 x 12 x 4
    k_wsplit_t<<<gt, 256, 0, stream>>>(Wq, Wk, Wv, coW, Whi, Wlo);
    k_wsplit_c<<<(AHc * HIDC / 8 + 255) / 256, 256, 0, stream>>>(pww, Whi, Wlo);
    k_depthwise<<<(MRr * HIDC / 4 + 255) / 256, 256, 0, stream>>>(Kin, dww, dwseq);
    k_bias<<<(5 * AHc + 255) / 256, 256, 0, stream>>>(cob, sepb, biasb);

    dim3 gg(AHc / 128, MRr / 128, 5);   // 3 x 32 x 5
    k_gemm5<<<gg, 256, 0, stream>>>(Q, Kin, V, dwseq, Whi, Wlo, biasb, mq);

    k_qkvsplit<<<(3 * MRr * AHc / 8 + 255) / 256, 256, 0, stream>>>(mq, mk, mv, qh, kh, kl, vh);
    k_ck<<<MRr, 64, 0, stream>>>(mkc, mq, ckW, ckb, cksm);
    k_convout<<<(MRr * AHc / 4 + 255) / 256, 256, 0, stream>>>(co, cksm, out);
    k_td<<<Bb, 256, 0, stream>>>(td, mask, tdsm);

    dim3 ga(Ss / 16, Bb * Hh);          // 64 x 24
    k_attn<<<ga, 256, 0, stream>>>(qh, kh, kl, vh, mask, tdsm, gam, out);
}